// Round 1
// 172.350 us; speedup vs baseline: 1.0293x; 1.0293x over previous
//
#include <hip/hip_runtime.h>
#include <math.h>

#define SEQ   3072
#define DM    1024
#define NH    16
#define DH    64
#define WIN   128
#define DIL   4
#define TSUB  768      // SEQ / DIL

typedef __attribute__((ext_vector_type(8))) short    short8;   // 8 bf16
typedef __attribute__((ext_vector_type(8))) _Float16 half8;    // 8 fp16
typedef __attribute__((ext_vector_type(4))) float    floatx4;  // MFMA C/D

__device__ __forceinline__ float bf2f(unsigned short u) {
    return __uint_as_float(((unsigned)u) << 16);
}
__device__ __forceinline__ unsigned short f2bf(float f) {   // RNE, finite inputs
    unsigned u = __float_as_uint(f);
    return (unsigned short)((u + 0x7FFFu + ((u >> 16) & 1u)) >> 16);
}
__device__ __forceinline__ unsigned short f2h(float f) {
    _Float16 h = (_Float16)f;
    return __builtin_bit_cast(unsigned short, h);
}

// async global->LDS, 16B/lane (used only by attn's K staging).
__device__ __forceinline__ void gload_lds16(const void* g, void* l) {
    __builtin_amdgcn_global_load_lds(
        (const __attribute__((address_space(1))) void*)g,
        (__attribute__((address_space(3))) void*)l, 16, 0, 0);
}

// ---------------------------------------------------------------------------
// fp32 -> bf16 conversion (restored: R8 showed fp32 inputs in the latency-
// bound GEMM loop double FETCH and cost 33 us; convert once, read bf16).
// ---------------------------------------------------------------------------
__global__ __launch_bounds__(256) void convert_kernel(
    const float* __restrict__ x,  const float* __restrict__ Wq,
    const float* __restrict__ Wk, const float* __restrict__ Wv,
    const float* __restrict__ Wo,
    ushort* __restrict__ xb,  ushort* __restrict__ Wqb,
    ushort* __restrict__ Wkb, ushort* __restrict__ Wvb,
    ushort* __restrict__ Wob)
{
    const float* s; ushort* d; int n;
    switch (blockIdx.y) {
        case 0: s = x;  d = xb;  n = SEQ * DM; break;
        case 1: s = Wq; d = Wqb; n = DM * DM;  break;
        case 2: s = Wk; d = Wkb; n = DM * DM;  break;
        case 3: s = Wv; d = Wvb; n = DM * DM;  break;
        default: s = Wo; d = Wob; n = DM * DM; break;
    }
    int i = (blockIdx.x * 256 + threadIdx.x) * 4;
    if (i >= n) return;
    float4 v = *(const float4*)&s[i];
    ushort4 o = { f2bf(v.x), f2bf(v.y), f2bf(v.z), f2bf(v.w) };
    *(ushort4*)&d[i] = o;
}

// ---------------------------------------------------------------------------
// QKV GEMM: 128(M) x 64(N) tile, BK=64. R9 findings: the old 128x128 version
// was latency-bound at OccupancyPercent=12 / MfmaUtil=15: (a) both template
// instantiations carried their own 32 KB of __shared__ -> LDS_Block_Size was
// 65536, capping 2 blocks/CU; (b) grid was only 576 blocks = 2.25/CU, so the
// 2-barrier lockstep loop had nothing to overlap with.
// Fix: single shared QkvSmem (24 KB) passed into both instantiations, and a
// half-width tile -> grid (16,24,3) = 1152 blocks = 4.5/CU. Wave tile 64x32
// (acc 4x2, ~90 VGPR) so 4 blocks/CU fit by both VGPR and LDS.
// Same 3-bit XOR swizzle pos = chunk ^ ((row>>1)&7) (R7-verified pattern
// class, 128-B rows -> 2 lanes/bank = free).
// ---------------------------------------------------------------------------
struct QkvSmem {
    ushort As[128][64];   // 16 KB
    ushort Bs[64][64];    //  8 KB
};

template<bool QSCALE>
__device__ __forceinline__ void gemm_qkv_body(QkvSmem& sm,
                                              const ushort* __restrict__ A,
                                              const ushort* __restrict__ W,
                                              const float* __restrict__ bias,
                                              const float* __restrict__ beta,
                                              ushort* __restrict__ C,
                                              int bx, int by)
{
    const int tid  = threadIdx.x;
    const int lane = tid & 63, w = tid >> 6;
    const int ln15 = lane & 15, quad = lane >> 4;
    const int wm = w >> 1, wn = w & 1;

    // A staging: thread t -> row t>>1 (0..127), half sh = t&1 (chunks 4sh..4sh+3)
    const int arow = tid >> 1;
    const int sh   = tid & 1;
    const int ska  = (arow >> 1) & 7;
    const ushort* aG = A + (size_t)(by * 128 + arow) * DM + sh * 32;
    ushort* aL[4];
#pragma unroll
    for (int c = 0; c < 4; ++c) {
        int pos = (4 * sh + c) ^ ska;
        aL[c] = &sm.As[arow][pos * 8];
    }

    // B staging: thread t -> row t>>2 (0..63), quarter sq = t&3 (chunks 2sq..2sq+1)
    const int brow = tid >> 2;
    const int sq   = tid & 3;
    const int skb  = (brow >> 1) & 7;
    const ushort* bG = W + (size_t)(bx * 64 + brow) * DM + sq * 16;
    ushort* bL[2];
#pragma unroll
    for (int c = 0; c < 2; ++c) {
        int pos = (2 * sq + c) ^ skb;
        bL[c] = &sm.Bs[brow][pos * 8];
    }

    const floatx4 zero = {0.f, 0.f, 0.f, 0.f};
    floatx4 acc[4][2];
#pragma unroll
    for (int i = 0; i < 4; ++i)
#pragma unroll
        for (int j = 0; j < 2; ++j) acc[i][j] = zero;

    // prologue: tile 0
    short8 ra[4], rb[2];
#pragma unroll
    for (int c = 0; c < 4; ++c) ra[c] = *(const short8*)(aG + 8 * c);
#pragma unroll
    for (int c = 0; c < 2; ++c) rb[c] = *(const short8*)(bG + 8 * c);
#pragma unroll
    for (int c = 0; c < 4; ++c) *(short8*)aL[c] = ra[c];
#pragma unroll
    for (int c = 0; c < 2; ++c) *(short8*)bL[c] = rb[c];
    __syncthreads();

    const int rf = (ln15 >> 1) & 7;            // frag-read swizzle key
#pragma unroll 2
    for (int k = 0; k < 16; ++k) {
        if (k < 15) {                          // loads for tile k+1 (regs)
            const ushort* aN = aG + (k + 1) * 64;
            const ushort* bN = bG + (k + 1) * 64;
#pragma unroll
            for (int c = 0; c < 4; ++c) ra[c] = *(const short8*)(aN + 8 * c);
#pragma unroll
            for (int c = 0; c < 2; ++c) rb[c] = *(const short8*)(bN + 8 * c);
        }
#pragma unroll
        for (int s = 0; s < 2; ++s) {          // two K=32 substeps
            short8 af[4], bf[2];
#pragma unroll
            for (int i = 0; i < 4; ++i)
                af[i] = *(const short8*)&sm.As[wm * 64 + i * 16 + ln15][((s * 4 + quad) ^ rf) * 8];
#pragma unroll
            for (int j = 0; j < 2; ++j)
                bf[j] = *(const short8*)&sm.Bs[wn * 32 + j * 16 + ln15][((s * 4 + quad) ^ rf) * 8];
#pragma unroll
            for (int i = 0; i < 4; ++i)
#pragma unroll
                for (int j = 0; j < 2; ++j)
                    acc[i][j] = __builtin_amdgcn_mfma_f32_16x16x32_bf16(af[i], bf[j], acc[i][j], 0, 0, 0);
        }
        __syncthreads();                       // tile-k LDS reads complete
        if (k < 15) {                          // vmcnt wait lands here (post-compute)
#pragma unroll
            for (int c = 0; c < 4; ++c) *(short8*)aL[c] = ra[c];
#pragma unroll
            for (int c = 0; c < 2; ++c) *(short8*)bL[c] = rb[c];
        }
        __syncthreads();                       // tile k+1 resident
    }

#pragma unroll
    for (int j = 0; j < 2; ++j) {
        const int col = bx * 64 + wn * 32 + j * 16 + ln15;
        const float b = bias[col];
        const float scale = QSCALE ? 0.125f * __expf(-beta[col >> 6]) : 1.0f;
#pragma unroll
        for (int i = 0; i < 4; ++i) {
            const int row0 = by * 128 + wm * 64 + i * 16 + quad * 4;
#pragma unroll
            for (int rg = 0; rg < 4; ++rg) {
                float vv = (acc[i][j][rg] + b) * scale;
                C[(size_t)(row0 + rg) * DM + col] = f2bf(vv);
            }
        }
    }
}

// grid (16, 24, 3): z selects Q/K/V. 1152 blocks (4.5/CU).
__global__ __launch_bounds__(256, 4) void qkv_kernel(
    const ushort* __restrict__ xb,
    const ushort* __restrict__ Wqb, const float* __restrict__ bq,
    const ushort* __restrict__ Wkb, const float* __restrict__ bk,
    const ushort* __restrict__ Wvb, const float* __restrict__ bv,
    const float* __restrict__ beta,
    ushort* __restrict__ q, ushort* __restrict__ k, ushort* __restrict__ v)
{
    __shared__ QkvSmem sm;                     // single 24 KB allocation shared
    const int z = blockIdx.z;                  // by BOTH instantiations below
    const ushort* W = (z == 0) ? Wqb : (z == 1) ? Wkb : Wvb;
    const float*  b = (z == 0) ? bq  : (z == 1) ? bk  : bv;
    ushort*       C = (z == 0) ? q   : (z == 1) ? k   : v;
    if (z == 0)
        gemm_qkv_body<true >(sm, xb, W, b, beta, C, blockIdx.x, blockIdx.y);
    else
        gemm_qkv_body<false>(sm, xb, W, b, nullptr, C, blockIdx.x, blockIdx.y);
}

// ---------------------------------------------------------------------------
// Output GEMM: 64x64 tile, BK=64, bf16 inputs, grid 768 (3 blocks/CU).
// Same reg-staged loop + 3-bit swizzle (rows are 128 B here too).
// 4 waves 2x2, wave tile 32x32, 2 substeps x 2x2 MFMAs.
// ---------------------------------------------------------------------------
__global__ __launch_bounds__(256) void out_kernel(
    const ushort* __restrict__ ctxb, const ushort* __restrict__ Wob,
    const float* __restrict__ bo, float* __restrict__ out)
{
    __shared__ ushort As[64][64];    // 8 KB
    __shared__ ushort Bs[64][64];    // 8 KB

    const int tid  = threadIdx.x;
    const int lane = tid & 63, w = tid >> 6;
    const int ln15 = lane & 15, quad = lane >> 4;
    const int wm = w >> 1, wn = w & 1;
    const int bx = blockIdx.x, by = blockIdx.y;

    // staging: thread t -> row t>>2 (0..63), quarter sq = t&3 (chunks 2sq,2sq+1)
    const int srow = tid >> 2;
    const int sq   = tid & 3;
    const int sk   = (srow >> 1) & 7;
    const ushort* aG = ctxb + (size_t)(by * 64 + srow) * DM + sq * 16;
    const ushort* bG = Wob  + (size_t)(bx * 64 + srow) * DM + sq * 16;
    ushort* aL[2]; ushort* bL[2];
#pragma unroll
    for (int c = 0; c < 2; ++c) {
        int pos = (2 * sq + c) ^ sk;
        aL[c] = &As[srow][pos * 8];
        bL[c] = &Bs[srow][pos * 8];
    }

    const floatx4 zero = {0.f, 0.f, 0.f, 0.f};
    floatx4 acc[2][2];
#pragma unroll
    for (int i = 0; i < 2; ++i)
#pragma unroll
        for (int j = 0; j < 2; ++j) acc[i][j] = zero;

    // prologue
    short8 ra[2], rb[2];
#pragma unroll
    for (int c = 0; c < 2; ++c) {
        ra[c] = *(const short8*)(aG + 8 * c);
        rb[c] = *(const short8*)(bG + 8 * c);
    }
#pragma unroll
    for (int c = 0; c < 2; ++c) { *(short8*)aL[c] = ra[c]; *(short8*)bL[c] = rb[c]; }
    __syncthreads();

    const int rf = (ln15 >> 1) & 7;
#pragma unroll 2
    for (int k = 0; k < 16; ++k) {
        if (k < 15) {
            const ushort* aN = aG + (k + 1) * 64;
            const ushort* bN = bG + (k + 1) * 64;
#pragma unroll
            for (int c = 0; c < 2; ++c) {
                ra[c] = *(const short8*)(aN + 8 * c);
                rb[c] = *(const short8*)(bN + 8 * c);
            }
        }
#pragma unroll
        for (int s = 0; s < 2; ++s) {
            short8 af[2], bf[2];
#pragma unroll
            for (int i = 0; i < 2; ++i)
                af[i] = *(const short8*)&As[wm * 32 + i * 16 + ln15][((s * 4 + quad) ^ rf) * 8];
#pragma unroll
            for (int j = 0; j < 2; ++j)
                bf[j] = *(const short8*)&Bs[wn * 32 + j * 16 + ln15][((s * 4 + quad) ^ rf) * 8];
#pragma unroll
            for (int i = 0; i < 2; ++i)
#pragma unroll
                for (int j = 0; j < 2; ++j)
                    acc[i][j] = __builtin_amdgcn_mfma_f32_16x16x32_bf16(af[i], bf[j], acc[i][j], 0, 0, 0);
        }
        __syncthreads();
        if (k < 15) {
#pragma unroll
            for (int c = 0; c < 2; ++c) { *(short8*)aL[c] = ra[c]; *(short8*)bL[c] = rb[c]; }
        }
        __syncthreads();
    }

#pragma unroll
    for (int j = 0; j < 2; ++j) {
        const int col = bx * 64 + wn * 32 + j * 16 + ln15;
        const float b = bo[col];
#pragma unroll
        for (int i = 0; i < 2; ++i) {
            const int row0 = by * 64 + wm * 32 + i * 16 + quad * 4;
#pragma unroll
            for (int rg = 0; rg < 4; ++rg)
                out[(size_t)(row0 + rg) * DM + col] = acc[i][j][rg] + b;
        }
    }
}

// ---------------------------------------------------------------------------
// MFMA attention (unchanged from R7/R8).
// ---------------------------------------------------------------------------
struct AttnSmem {
    union {
        ushort Ks[192 * 64];        // [key][dg] ; dg holds dims 8*(dg^(key&7))
        ushort Vt[6 * 4 * 64 * 8];  // [kc][dt][lane][8] fp16, lane-linear
    } u;
    float S[32][195];
    float Rsum[32];
};

__global__ __launch_bounds__(256) void attn_kernel(
    const ushort* __restrict__ q, const ushort* __restrict__ k,
    const ushort* __restrict__ v, ushort* __restrict__ ctx)
{
    __shared__ AttnSmem sm;

    const int tid  = threadIdx.x;
    const int lane = tid & 63, w = tid >> 6;
    const int ln15 = lane & 15, quad = lane >> 4;
    const int t0   = blockIdx.x * 32;
    const int r    = blockIdx.y;
    const int h    = blockIdx.z;
    const int hoff = h * DH;

    // ---- stage K (192 keys x 64 dims) via glds, 6 ops/wave -----------------
    {
        const int kr = lane >> 3;                   // key-in-op 0..7
        const int swz = ((lane & 7) ^ kr) * 8;      // XOR swizzle on global dim
#pragma unroll
        for (int ci = w * 6; ci < w * 6 + 6; ++ci) {
            int key = ci * 8 + kr;
            long grow = 4L * (t0 - 160 + key) + r;  // may be negative -> q buffer
            gload_lds16(k + grow * DM + hoff + swz, &sm.u.Ks[ci * 512]);
        }
    }

    // ---- Q A-frags direct from global (wave w owns qtile w>>1) -------------
    const int qt = w >> 1;
    short8 qf0, qf1;
    {
        int qrow = qt * 16 + ln15;
        const ushort* gq = q + (4L * (t0 + qrow) + r) * DM + hoff + quad * 8;
        qf0 = *(const short8*)gq;
        qf1 = *(const short8*)(gq + 32);
    }

    // ---- V loads into registers (writes to LDS deferred past barrier 2) ----
    short8 vreg[6];
#pragma unroll
    for (int it = 0; it < 6; ++it) {
        int idx = it * 256 + tid;                   // 0..1535
        int key = idx >> 3, d0 = (idx & 7) * 8;
        long grow = 4L * (t0 - 160 + key) + r;
        vreg[it] = *(const short8*)(v + grow * DM + hoff + d0);
    }

    __syncthreads();   // barrier 1: Ks staged (vmcnt drained by sync)

    // ---- QK^T: wave w -> qtile w>>1, ktiles (w&1)*6 .. +5 ------------------
    {
        const floatx4 zero = {0.f, 0.f, 0.f, 0.f};
        const int kt0 = (w & 1) * 6;
        const int lb  = ln15 & 7;
#pragma unroll
        for (int kk2 = 0; kk2 < 6; ++kk2) {
            const int kt  = kt0 + kk2;
            const int key = kt * 16 + ln15;
            short8 b0 = *(const short8*)&sm.u.Ks[key * 64 + ((quad ^ lb) << 3)];
            short8 b1 = *(const short8*)&sm.u.Ks[key * 64 + (((4 + quad) ^ lb) << 3)];
            floatx4 acc = zero;
            acc = __builtin_amdgcn_mfma_f32_16x16x32_bf16(qf0, b0, acc, 0, 0, 0);
            acc = __builtin_amdgcn_mfma_f32_16x16x32_bf16(qf1, b1, acc, 0, 0, 0);
            const int tp = t0 - 160 + key;          // key slot time
#pragma unroll
            for (int rg = 0; rg < 4; ++rg) {
                int qrow = qt * 16 + quad * 4 + rg;
                int tq = t0 + qrow;
                bool ok = (tp >= 0) && (tp <= tq) && (tp > tq - WIN);
                sm.S[qrow][key] = ok ? acc[rg] : -1e30f;
            }
        }
    }

    __syncthreads();   // barrier 2: S complete, Ks reads done (Vt may alias)

    // ---- V transpose -> frag-linear fp16 LDS -------------------------------
#pragma unroll
    for (int it = 0; it < 6; ++it) {
        int idx = it * 256 + tid;
        int key = idx >> 3, d0 = (idx & 7) * 8;
        int kc = key >> 5, qd = (key >> 3) & 3, jj = key & 7;
        short8 sv = vreg[it];
#pragma unroll
        for (int u = 0; u < 8; ++u) {
            int dim = d0 + u, dt = dim >> 4, ln = dim & 15;
            sm.u.Vt[(kc * 4 + dt) * 512 + (qd * 16 + ln) * 8 + jj] =
                f2h(bf2f((unsigned short)sv[u]));
        }
    }

    // ---- softmax: 8 threads/row, stride-8 slot ownership -------------------
    {
        const int sq = tid >> 3, part = tid & 7;
        float m = -1e30f;
#pragma unroll
        for (int j = 0; j < 24; ++j) m = fmaxf(m, sm.S[sq][part + 8 * j]);
#pragma unroll
        for (int o = 1; o < 8; o <<= 1) m = fmaxf(m, __shfl_xor(m, o));
        float sum = 0.f;
#pragma unroll
        for (int j = 0; j < 24; ++j) {
            int ks = part + 8 * j;
            float e = __expf(sm.S[sq][ks] - m);
            sm.S[sq][ks] = e;
            sum += e;
        }
#pragma unroll
        for (int o = 1; o < 8; o <<= 1) sum += __shfl_xor(sum, o);
        if (part == 0) sm.Rsum[sq] = 1.0f / sum;
    }

    __syncthreads();   // barrier 3: Vt + P(S) + Rsum ready

    // ---- PV: wave w -> qtile w&1, dtiles (w>>1)*2 .. +1 --------------------
    {
        const floatx4 zero = {0.f, 0.f, 0.f, 0.f};
        const int qtp = w & 1, dh = w >> 1;
        floatx4 o0 = zero, o1 = zero;
#pragma unroll
        for (int kc = 0; kc < 6; ++kc) {
            const float* ps = &sm.S[qtp * 16 + ln15][kc * 32 + quad * 8];
            half8 pa;
#pragma unroll
            for (int u = 0; u < 8; ++u) pa[u] = (_Float16)ps[u];
            half8 vb0 = *(const half8*)&sm.u.Vt[(kc * 4 + dh * 2 + 0) * 512 + lane * 8];
            half8 vb1 = *(const half8*)&sm.u.Vt[(kc * 4 + dh * 2 + 1) * 512 + lane * 8];
            o0 = __builtin_amdgcn_mfma_f32_16x16x32_f16(pa, vb0, o0, 0, 0, 0);
            o1 = __builtin_amdgcn_mfma_f32_16x16x32_f16(pa, vb1, o1, 0, 0, 0);
        }
#pragma unroll
        for (int rg = 0; rg < 4; ++rg) {
            int qrow = qtp * 16 + quad * 4 + rg;
            float rs = sm.Rsum[qrow];
            long orow = 4L * (t0 + qrow) + r;
            ushort* cp = ctx + orow * DM + hoff + dh * 32 + ln15;
            cp[0]  = f2bf(o0[rg] * rs);
            cp[16] = f2bf(o1[rg] * rs);
        }
    }
}

// ---------------------------------------------------------------------------
// ws layout (all bf16): q, k, v, ctx (SEQ*DM each), x, Wq, Wk, Wv, Wo.
// ---------------------------------------------------------------------------
extern "C" void kernel_launch(void* const* d_in, const int* in_sizes, int n_in,
                              void* d_out, int out_size, void* d_ws, size_t ws_size,
                              hipStream_t stream)
{
    const float* x    = (const float*)d_in[0];
    const float* beta = (const float*)d_in[1];
    const float* Wq   = (const float*)d_in[2];
    const float* bq   = (const float*)d_in[3];
    const float* Wk   = (const float*)d_in[4];
    const float* bk   = (const float*)d_in[5];
    const float* Wv   = (const float*)d_in[6];
    const float* bv   = (const float*)d_in[7];
    const float* Wo   = (const float*)d_in[8];
    const float* bo   = (const float*)d_in[9];

    ushort* qb   = (ushort*)d_ws;
    ushort* kb   = qb   + (size_t)SEQ * DM;
    ushort* vb   = kb   + (size_t)SEQ * DM;
    ushort* ctxb = vb   + (size_t)SEQ * DM;
    ushort* xb   = ctxb + (size_t)SEQ * DM;
    ushort* Wqb  = xb   + (size_t)SEQ * DM;
    ushort* Wkb  = Wqb  + (size_t)DM * DM;
    ushort* Wvb  = Wkb  + (size_t)DM * DM;
    ushort* Wob  = Wvb  + (size_t)DM * DM;
    float*  out  = (float*)d_out;

    dim3 gcv(SEQ * DM / 4 / 256, 5);
    convert_kernel<<<gcv, 256, 0, stream>>>(x, Wq, Wk, Wv, Wo, xb, Wqb, Wkb, Wvb, Wob);

    dim3 gqkv(DM / 64, SEQ / 128, 3);           // (16, 24, 3) = 1152 blocks
    qkv_kernel<<<gqkv, 256, 0, stream>>>(xb, Wqb, bq, Wkb, bk, Wvb, bv, beta, qb, kb, vb);

    dim3 gattn(TSUB / 32, DIL, NH);             // (24, 4, 16) = 1536 blocks
    attn_kernel<<<gattn, 256, 0, stream>>>(qb, kb, vb, ctxb);

    dim3 gout(DM / 64, SEQ / 64);               // (16, 48) = 768 blocks
    out_kernel<<<gout, 256, 0, stream>>>(ctxb, Wob, bo, out);
}

// Round 2
// 165.044 us; speedup vs baseline: 1.0749x; 1.0443x over previous
//
#include <hip/hip_runtime.h>
#include <math.h>

#define SEQ   3072
#define DM    1024
#define NH    16
#define DH    64
#define WIN   128
#define DIL   4
#define TSUB  768      // SEQ / DIL

typedef __attribute__((ext_vector_type(8))) short    short8;   // 8 bf16
typedef __attribute__((ext_vector_type(8))) _Float16 half8;    // 8 fp16
typedef __attribute__((ext_vector_type(4))) float    floatx4;  // MFMA C/D

__device__ __forceinline__ float bf2f(unsigned short u) {
    return __uint_as_float(((unsigned)u) << 16);
}
__device__ __forceinline__ unsigned short f2bf(float f) {   // RNE, finite inputs
    unsigned u = __float_as_uint(f);
    return (unsigned short)((u + 0x7FFFu + ((u >> 16) & 1u)) >> 16);
}
__device__ __forceinline__ unsigned short f2h(float f) {
    _Float16 h = (_Float16)f;
    return __builtin_bit_cast(unsigned short, h);
}

// async global->LDS, 16B/lane. LDS dest is WAVE-UNIFORM base + lane*16
// (hardware adds the lane offset); global src is per-lane.
__device__ __forceinline__ void gload_lds16(const void* g, void* l) {
    __builtin_amdgcn_global_load_lds(
        (const __attribute__((address_space(1))) void*)g,
        (__attribute__((address_space(3))) void*)l, 16, 0, 0);
}

// ---------------------------------------------------------------------------
// fp32 -> bf16 conversion (R8: fp32 inputs in the GEMM loop double FETCH and
// cost 33 us; convert once, read bf16).
// ---------------------------------------------------------------------------
__global__ __launch_bounds__(256) void convert_kernel(
    const float* __restrict__ x,  const float* __restrict__ Wq,
    const float* __restrict__ Wk, const float* __restrict__ Wv,
    const float* __restrict__ Wo,
    ushort* __restrict__ xb,  ushort* __restrict__ Wqb,
    ushort* __restrict__ Wkb, ushort* __restrict__ Wvb,
    ushort* __restrict__ Wob)
{
    const float* s; ushort* d; int n;
    switch (blockIdx.y) {
        case 0: s = x;  d = xb;  n = SEQ * DM; break;
        case 1: s = Wq; d = Wqb; n = DM * DM;  break;
        case 2: s = Wk; d = Wkb; n = DM * DM;  break;
        case 3: s = Wv; d = Wvb; n = DM * DM;  break;
        default: s = Wo; d = Wob; n = DM * DM; break;
    }
    int i = (blockIdx.x * 256 + threadIdx.x) * 4;
    if (i >= n) return;
    float4 v = *(const float4*)&s[i];
    ushort4 o = { f2bf(v.x), f2bf(v.y), f2bf(v.z), f2bf(v.w) };
    *(ushort4*)&d[i] = o;
}

// ---------------------------------------------------------------------------
// QKV GEMM, R11: minimum-2-phase DMA pipeline (guide T3 recipe).
// R10 lesson: occupancy 2->4 blocks/CU bought only ~5 us -- the 2-barrier
// reg-staged loop is ITERATION-latency-bound (2 barriers + vmcnt drain +
// ds_write on the critical path each K-step), so more resident blocks just
// meant more blocks to run. This version:
//   - double-buffered LDS (48 KB), ONE barrier per K-iteration;
//   - staging via global_load_lds width-16: LDS dest linear (wave-uniform
//     base + lane*16, i.e. lane -> row l>>3, chunk l&7 of 8 consecutive
//     128-B rows), swizzle applied by PERMUTING THE GLOBAL SOURCE chunk:
//     g_chunk = (l&7) ^ ((row>>1)&7). XOR is an involution, so the frag
//     read key rf=(ln15>>1)&7 (rows ln15 mod 16, +16*i keeps key invariant)
//     reads back the logical chunk. Per-8-lane group still covers one full
//     128-B global line -> perfectly coalesced.
//   - prefetch for tile t+1 issues BEFORE tile-t compute; the compiler's
//     mandatory vmcnt(0) lands at the single end-of-iter barrier, so the
//     load latency hides under 16 MFMAs + 12 ds_read_b128.
//   - kills the per-iteration ds_write staging (round-0's 2.36M bank-conflict
//     cycles) and ~24 staging VGPRs.
// ---------------------------------------------------------------------------
struct QkvSmem {
    ushort As[2][128][64];   // 2 x 16 KB
    ushort Bs[2][64][64];    // 2 x  8 KB
};

template<bool QSCALE>
__device__ __forceinline__ void gemm_qkv_body(QkvSmem& sm,
                                              const ushort* __restrict__ A,
                                              const ushort* __restrict__ W,
                                              const float* __restrict__ bias,
                                              const float* __restrict__ beta,
                                              ushort* __restrict__ C,
                                              int bx, int by)
{
    const int tid  = threadIdx.x;
    const int lane = tid & 63, w = tid >> 6;
    const int ln15 = lane & 15, quad = lane >> 4;
    const int wm = w >> 1, wn = w & 1;

    // DMA staging geometry: one gload_lds = 64 lanes x 16B = 8 rows of 128 B.
    // Wave w stages As rows w*32..w*32+31 (4 ops) + Bs rows w*16..+15 (2 ops).
    const int rl = lane >> 3, cl = lane & 7;
    const ushort* aRow[4];
#pragma unroll
    for (int i = 0; i < 4; ++i) {
        int row   = w * 32 + 8 * i + rl;
        int chunk = cl ^ ((row >> 1) & 7);              // inverse-swizzled src
        aRow[i] = A + (size_t)(by * 128 + row) * DM + chunk * 8;
    }
    const ushort* bRow[2];
#pragma unroll
    for (int i = 0; i < 2; ++i) {
        int row   = w * 16 + 8 * i + rl;
        int chunk = cl ^ ((row >> 1) & 7);
        bRow[i] = W + (size_t)(bx * 64 + row) * DM + chunk * 8;
    }

    const floatx4 zero = {0.f, 0.f, 0.f, 0.f};
    floatx4 acc[4][2];
#pragma unroll
    for (int i = 0; i < 4; ++i)
#pragma unroll
        for (int j = 0; j < 2; ++j) acc[i][j] = zero;

    // prologue: stage tile 0 into buffer 0
#pragma unroll
    for (int i = 0; i < 4; ++i) gload_lds16(aRow[i], &sm.As[0][w * 32 + 8 * i][0]);
#pragma unroll
    for (int i = 0; i < 2; ++i) gload_lds16(bRow[i], &sm.Bs[0][w * 16 + 8 * i][0]);
    __syncthreads();                                    // drains vmcnt -> buf0 ready

    const int rf = (ln15 >> 1) & 7;                     // frag-read swizzle key
#pragma unroll 2
    for (int t = 0; t < 16; ++t) {
        const int cur = t & 1, nxt = cur ^ 1;
        if (t < 15) {                                   // issue prefetch FIRST
            const int ko = (t + 1) * 64;
#pragma unroll
            for (int i = 0; i < 4; ++i) gload_lds16(aRow[i] + ko, &sm.As[nxt][w * 32 + 8 * i][0]);
#pragma unroll
            for (int i = 0; i < 2; ++i) gload_lds16(bRow[i] + ko, &sm.Bs[nxt][w * 16 + 8 * i][0]);
        }
#pragma unroll
        for (int s = 0; s < 2; ++s) {                   // two K=32 substeps
            short8 af[4], bf[2];
#pragma unroll
            for (int i = 0; i < 4; ++i)
                af[i] = *(const short8*)&sm.As[cur][wm * 64 + i * 16 + ln15][((s * 4 + quad) ^ rf) * 8];
#pragma unroll
            for (int j = 0; j < 2; ++j)
                bf[j] = *(const short8*)&sm.Bs[cur][wn * 32 + j * 16 + ln15][((s * 4 + quad) ^ rf) * 8];
#pragma unroll
            for (int i = 0; i < 4; ++i)
#pragma unroll
                for (int j = 0; j < 2; ++j)
                    acc[i][j] = __builtin_amdgcn_mfma_f32_16x16x32_bf16(af[i], bf[j], acc[i][j], 0, 0, 0);
        }
        __syncthreads();   // single barrier: drains vmcnt (prefetch done) +
                           // lgkm (tile-t reads done) -> next iter may write cur
    }

#pragma unroll
    for (int j = 0; j < 2; ++j) {
        const int col = bx * 64 + wn * 32 + j * 16 + ln15;
        const float b = bias[col];
        const float scale = QSCALE ? 0.125f * __expf(-beta[col >> 6]) : 1.0f;
#pragma unroll
        for (int i = 0; i < 4; ++i) {
            const int row0 = by * 128 + wm * 64 + i * 16 + quad * 4;
#pragma unroll
            for (int rg = 0; rg < 4; ++rg) {
                float vv = (acc[i][j][rg] + b) * scale;
                C[(size_t)(row0 + rg) * DM + col] = f2bf(vv);
            }
        }
    }
}

// grid (16, 24, 3): z selects Q/K/V. 1152 blocks; 48 KB LDS -> 3 blocks/CU.
__global__ __launch_bounds__(256, 3) void qkv_kernel(
    const ushort* __restrict__ xb,
    const ushort* __restrict__ Wqb, const float* __restrict__ bq,
    const ushort* __restrict__ Wkb, const float* __restrict__ bk,
    const ushort* __restrict__ Wvb, const float* __restrict__ bv,
    const float* __restrict__ beta,
    ushort* __restrict__ q, ushort* __restrict__ k, ushort* __restrict__ v)
{
    __shared__ QkvSmem sm;                     // single allocation, shared by
    const int z = blockIdx.z;                  // BOTH instantiations below
    const ushort* W = (z == 0) ? Wqb : (z == 1) ? Wkb : Wvb;
    const float*  b = (z == 0) ? bq  : (z == 1) ? bk  : bv;
    ushort*       C = (z == 0) ? q   : (z == 1) ? k   : v;
    if (z == 0)
        gemm_qkv_body<true >(sm, xb, W, b, beta, C, blockIdx.x, blockIdx.y);
    else
        gemm_qkv_body<false>(sm, xb, W, b, nullptr, C, blockIdx.x, blockIdx.y);
}

// ---------------------------------------------------------------------------
// Output GEMM: 64x64 tile, BK=64, grid 768 (3/CU). Same minimum-2-phase DMA
// pipeline as qkv: dbuf LDS 32 KB, one barrier/iter, pre-swizzled gload_lds.
// 4 waves 2x2, wave tile 32x32.
// ---------------------------------------------------------------------------
__global__ __launch_bounds__(256, 3) void out_kernel(
    const ushort* __restrict__ ctxb, const ushort* __restrict__ Wob,
    const float* __restrict__ bo, float* __restrict__ out)
{
    __shared__ ushort As[2][64][64];    // 16 KB
    __shared__ ushort Bs[2][64][64];    // 16 KB

    const int tid  = threadIdx.x;
    const int lane = tid & 63, w = tid >> 6;
    const int ln15 = lane & 15, quad = lane >> 4;
    const int wm = w >> 1, wn = w & 1;
    const int bx = blockIdx.x, by = blockIdx.y;

    // wave w stages As rows w*16..+15 (2 ops) and Bs rows w*16..+15 (2 ops)
    const int rl = lane >> 3, cl = lane & 7;
    const ushort* aRow[2]; const ushort* bRow[2];
#pragma unroll
    for (int i = 0; i < 2; ++i) {
        int row   = w * 16 + 8 * i + rl;
        int chunk = cl ^ ((row >> 1) & 7);
        aRow[i] = ctxb + (size_t)(by * 64 + row) * DM + chunk * 8;
        bRow[i] = Wob  + (size_t)(bx * 64 + row) * DM + chunk * 8;
    }

    const floatx4 zero = {0.f, 0.f, 0.f, 0.f};
    floatx4 acc[2][2];
#pragma unroll
    for (int i = 0; i < 2; ++i)
#pragma unroll
        for (int j = 0; j < 2; ++j) acc[i][j] = zero;

    // prologue
#pragma unroll
    for (int i = 0; i < 2; ++i) {
        gload_lds16(aRow[i], &As[0][w * 16 + 8 * i][0]);
        gload_lds16(bRow[i], &Bs[0][w * 16 + 8 * i][0]);
    }
    __syncthreads();

    const int rf = (ln15 >> 1) & 7;
#pragma unroll 2
    for (int t = 0; t < 16; ++t) {
        const int cur = t & 1, nxt = cur ^ 1;
        if (t < 15) {
            const int ko = (t + 1) * 64;
#pragma unroll
            for (int i = 0; i < 2; ++i) {
                gload_lds16(aRow[i] + ko, &As[nxt][w * 16 + 8 * i][0]);
                gload_lds16(bRow[i] + ko, &Bs[nxt][w * 16 + 8 * i][0]);
            }
        }
#pragma unroll
        for (int s = 0; s < 2; ++s) {
            short8 af[2], bf[2];
#pragma unroll
            for (int i = 0; i < 2; ++i)
                af[i] = *(const short8*)&As[cur][wm * 32 + i * 16 + ln15][((s * 4 + quad) ^ rf) * 8];
#pragma unroll
            for (int j = 0; j < 2; ++j)
                bf[j] = *(const short8*)&Bs[cur][wn * 32 + j * 16 + ln15][((s * 4 + quad) ^ rf) * 8];
#pragma unroll
            for (int i = 0; i < 2; ++i)
#pragma unroll
                for (int j = 0; j < 2; ++j)
                    acc[i][j] = __builtin_amdgcn_mfma_f32_16x16x32_bf16(af[i], bf[j], acc[i][j], 0, 0, 0);
        }
        __syncthreads();
    }

#pragma unroll
    for (int j = 0; j < 2; ++j) {
        const int col = bx * 64 + wn * 32 + j * 16 + ln15;
        const float b = bo[col];
#pragma unroll
        for (int i = 0; i < 2; ++i) {
            const int row0 = by * 64 + wm * 32 + i * 16 + quad * 4;
#pragma unroll
            for (int rg = 0; rg < 4; ++rg)
                out[(size_t)(row0 + rg) * DM + col] = acc[i][j][rg] + b;
        }
    }
}

// ---------------------------------------------------------------------------
// MFMA attention (unchanged).
// ---------------------------------------------------------------------------
struct AttnSmem {
    union {
        ushort Ks[192 * 64];        // [key][dg] ; dg holds dims 8*(dg^(key&7))
        ushort Vt[6 * 4 * 64 * 8];  // [kc][dt][lane][8] fp16, lane-linear
    } u;
    float S[32][195];
    float Rsum[32];
};

__global__ __launch_bounds__(256) void attn_kernel(
    const ushort* __restrict__ q, const ushort* __restrict__ k,
    const ushort* __restrict__ v, ushort* __restrict__ ctx)
{
    __shared__ AttnSmem sm;

    const int tid  = threadIdx.x;
    const int lane = tid & 63, w = tid >> 6;
    const int ln15 = lane & 15, quad = lane >> 4;
    const int t0   = blockIdx.x * 32;
    const int r    = blockIdx.y;
    const int h    = blockIdx.z;
    const int hoff = h * DH;

    // ---- stage K (192 keys x 64 dims) via glds, 6 ops/wave -----------------
    {
        const int kr = lane >> 3;                   // key-in-op 0..7
        const int swz = ((lane & 7) ^ kr) * 8;      // XOR swizzle on global dim
#pragma unroll
        for (int ci = w * 6; ci < w * 6 + 6; ++ci) {
            int key = ci * 8 + kr;
            long grow = 4L * (t0 - 160 + key) + r;  // may be negative -> q buffer
            gload_lds16(k + grow * DM + hoff + swz, &sm.u.Ks[ci * 512]);
        }
    }

    // ---- Q A-frags direct from global (wave w owns qtile w>>1) -------------
    const int qt = w >> 1;
    short8 qf0, qf1;
    {
        int qrow = qt * 16 + ln15;
        const ushort* gq = q + (4L * (t0 + qrow) + r) * DM + hoff + quad * 8;
        qf0 = *(const short8*)gq;
        qf1 = *(const short8*)(gq + 32);
    }

    // ---- V loads into registers (writes to LDS deferred past barrier 2) ----
    short8 vreg[6];
#pragma unroll
    for (int it = 0; it < 6; ++it) {
        int idx = it * 256 + tid;                   // 0..1535
        int key = idx >> 3, d0 = (idx & 7) * 8;
        long grow = 4L * (t0 - 160 + key) + r;
        vreg[it] = *(const short8*)(v + grow * DM + hoff + d0);
    }

    __syncthreads();   // barrier 1: Ks staged (vmcnt drained by sync)

    // ---- QK^T: wave w -> qtile w>>1, ktiles (w&1)*6 .. +5 ------------------
    {
        const floatx4 zero = {0.f, 0.f, 0.f, 0.f};
        const int kt0 = (w & 1) * 6;
        const int lb  = ln15 & 7;
#pragma unroll
        for (int kk2 = 0; kk2 < 6; ++kk2) {
            const int kt  = kt0 + kk2;
            const int key = kt * 16 + ln15;
            short8 b0 = *(const short8*)&sm.u.Ks[key * 64 + ((quad ^ lb) << 3)];
            short8 b1 = *(const short8*)&sm.u.Ks[key * 64 + (((4 + quad) ^ lb) << 3)];
            floatx4 acc = zero;
            acc = __builtin_amdgcn_mfma_f32_16x16x32_bf16(qf0, b0, acc, 0, 0, 0);
            acc = __builtin_amdgcn_mfma_f32_16x16x32_bf16(qf1, b1, acc, 0, 0, 0);
            const int tp = t0 - 160 + key;          // key slot time
#pragma unroll
            for (int rg = 0; rg < 4; ++rg) {
                int qrow = qt * 16 + quad * 4 + rg;
                int tq = t0 + qrow;
                bool ok = (tp >= 0) && (tp <= tq) && (tp > tq - WIN);
                sm.S[qrow][key] = ok ? acc[rg] : -1e30f;
            }
        }
    }

    __syncthreads();   // barrier 2: S complete, Ks reads done (Vt may alias)

    // ---- V transpose -> frag-linear fp16 LDS -------------------------------
#pragma unroll
    for (int it = 0; it < 6; ++it) {
        int idx = it * 256 + tid;
        int key = idx >> 3, d0 = (idx & 7) * 8;
        int kc = key >> 5, qd = (key >> 3) & 3, jj = key & 7;
        short8 sv = vreg[it];
#pragma unroll
        for (int u = 0; u < 8; ++u) {
            int dim = d0 + u, dt = dim >> 4, ln = dim & 15;
            sm.u.Vt[(kc * 4 + dt) * 512 + (qd * 16 + ln) * 8 + jj] =
                f2h(bf2f((unsigned short)sv[u]));
        }
    }

    // ---- softmax: 8 threads/row, stride-8 slot ownership -------------------
    {
        const int sq = tid >> 3, part = tid & 7;
        float m = -1e30f;
#pragma unroll
        for (int j = 0; j < 24; ++j) m = fmaxf(m, sm.S[sq][part + 8 * j]);
#pragma unroll
        for (int o = 1; o < 8; o <<= 1) m = fmaxf(m, __shfl_xor(m, o));
        float sum = 0.f;
#pragma unroll
        for (int j = 0; j < 24; ++j) {
            int ks = part + 8 * j;
            float e = __expf(sm.S[sq][ks] - m);
            sm.S[sq][ks] = e;
            sum += e;
        }
#pragma unroll
        for (int o = 1; o < 8; o <<= 1) sum += __shfl_xor(sum, o);
        if (part == 0) sm.Rsum[sq] = 1.0f / sum;
    }

    __syncthreads();   // barrier 3: Vt + P(S) + Rsum ready

    // ---- PV: wave w -> qtile w&1, dtiles (w>>1)*2 .. +1 --------------------
    {
        const floatx4 zero = {0.f, 0.f, 0.f, 0.f};
        const int qtp = w & 1, dh = w >> 1;
        floatx4 o0 = zero, o1 = zero;
#pragma unroll
        for (int kc = 0; kc < 6; ++kc) {
            const float* ps = &sm.S[qtp * 16 + ln15][kc * 32 + quad * 8];
            half8 pa;
#pragma unroll
            for (int u = 0; u < 8; ++u) pa[u] = (_Float16)ps[u];
            half8 vb0 = *(const half8*)&sm.u.Vt[(kc * 4 + dh * 2 + 0) * 512 + lane * 8];
            half8 vb1 = *(const half8*)&sm.u.Vt[(kc * 4 + dh * 2 + 1) * 512 + lane * 8];
            o0 = __builtin_amdgcn_mfma_f32_16x16x32_f16(pa, vb0, o0, 0, 0, 0);
            o1 = __builtin_amdgcn_mfma_f32_16x16x32_f16(pa, vb1, o1, 0, 0, 0);
        }
#pragma unroll
        for (int rg = 0; rg < 4; ++rg) {
            int qrow = qtp * 16 + quad * 4 + rg;
            float rs = sm.Rsum[qrow];
            long orow = 4L * (t0 + qrow) + r;
            ushort* cp = ctx + orow * DM + hoff + dh * 32 + ln15;
            cp[0]  = f2bf(o0[rg] * rs);
            cp[16] = f2bf(o1[rg] * rs);
        }
    }
}

// ---------------------------------------------------------------------------
// ws layout (all bf16): q, k, v, ctx (SEQ*DM each), x, Wq, Wk, Wv, Wo.
// ---------------------------------------------------------------------------
extern "C" void kernel_launch(void* const* d_in, const int* in_sizes, int n_in,
                              void* d_out, int out_size, void* d_ws, size_t ws_size,
                              hipStream_t stream)
{
    const float* x    = (const float*)d_in[0];
    const float* beta = (const float*)d_in[1];
    const float* Wq   = (const float*)d_in[2];
    const float* bq   = (const float*)d_in[3];
    const float* Wk   = (const float*)d_in[4];
    const float* bk   = (const float*)d_in[5];
    const float* Wv   = (const float*)d_in[6];
    const float* bv   = (const float*)d_in[7];
    const float* Wo   = (const float*)d_in[8];
    const float* bo   = (const float*)d_in[9];

    ushort* qb   = (ushort*)d_ws;
    ushort* kb   = qb   + (size_t)SEQ * DM;
    ushort* vb   = kb   + (size_t)SEQ * DM;
    ushort* ctxb = vb   + (size_t)SEQ * DM;
    ushort* xb   = ctxb + (size_t)SEQ * DM;
    ushort* Wqb  = xb   + (size_t)SEQ * DM;
    ushort* Wkb  = Wqb  + (size_t)DM * DM;
    ushort* Wvb  = Wkb  + (size_t)DM * DM;
    ushort* Wob  = Wvb  + (size_t)DM * DM;
    float*  out  = (float*)d_out;

    dim3 gcv(SEQ * DM / 4 / 256, 5);
    convert_kernel<<<gcv, 256, 0, stream>>>(x, Wq, Wk, Wv, Wo, xb, Wqb, Wkb, Wvb, Wob);

    dim3 gqkv(DM / 64, SEQ / 128, 3);           // (16, 24, 3) = 1152 blocks
    qkv_kernel<<<gqkv, 256, 0, stream>>>(xb, Wqb, bq, Wkb, bk, Wvb, bv, beta, qb, kb, vb);

    dim3 gattn(TSUB / 32, DIL, NH);             // (24, 4, 16) = 1536 blocks
    attn_kernel<<<gattn, 256, 0, stream>>>(qb, kb, vb, ctxb);

    dim3 gout(DM / 64, SEQ / 64);               // (16, 48) = 768 blocks
    out_kernel<<<gout, 256, 0, stream>>>(ctxb, Wob, bo, out);
}

// Round 3
// 153.055 us; speedup vs baseline: 1.1591x; 1.0783x over previous
//
#include <hip/hip_runtime.h>
#include <math.h>

#define SEQ   3072
#define DM    1024
#define NH    16
#define DH    64
#define WIN   128
#define DIL   4
#define TSUB  768      // SEQ / DIL

typedef __attribute__((ext_vector_type(8))) short    short8;   // 8 bf16
typedef __attribute__((ext_vector_type(8))) _Float16 half8;    // 8 fp16
typedef __attribute__((ext_vector_type(4))) _Float16 half4;    // 4 fp16 (64b)
typedef __attribute__((ext_vector_type(4))) float    floatx4;  // MFMA C/D

__device__ __forceinline__ float bf2f(unsigned short u) {
    return __uint_as_float(((unsigned)u) << 16);
}
__device__ __forceinline__ unsigned short f2bf(float f) {   // RNE, finite inputs
    unsigned u = __float_as_uint(f);
    return (unsigned short)((u + 0x7FFFu + ((u >> 16) & 1u)) >> 16);
}
__device__ __forceinline__ unsigned short f2h(float f) {
    _Float16 h = (_Float16)f;
    return __builtin_bit_cast(unsigned short, h);
}

// async global->LDS, 16B/lane. LDS dest is WAVE-UNIFORM base + lane*16
// (hardware adds the lane offset); global src is per-lane.
__device__ __forceinline__ void gload_lds16(const void* g, void* l) {
    __builtin_amdgcn_global_load_lds(
        (const __attribute__((address_space(1))) void*)g,
        (__attribute__((address_space(3))) void*)l, 16, 0, 0);
}

// ---------------------------------------------------------------------------
// fp32 -> bf16 conversion (R8: fp32 inputs in the GEMM loop double FETCH and
// cost 33 us; convert once, read bf16).
// ---------------------------------------------------------------------------
__global__ __launch_bounds__(256) void convert_kernel(
    const float* __restrict__ x,  const float* __restrict__ Wq,
    const float* __restrict__ Wk, const float* __restrict__ Wv,
    const float* __restrict__ Wo,
    ushort* __restrict__ xb,  ushort* __restrict__ Wqb,
    ushort* __restrict__ Wkb, ushort* __restrict__ Wvb,
    ushort* __restrict__ Wob)
{
    const float* s; ushort* d; int n;
    switch (blockIdx.y) {
        case 0: s = x;  d = xb;  n = SEQ * DM; break;
        case 1: s = Wq; d = Wqb; n = DM * DM;  break;
        case 2: s = Wk; d = Wkb; n = DM * DM;  break;
        case 3: s = Wv; d = Wvb; n = DM * DM;  break;
        default: s = Wo; d = Wob; n = DM * DM; break;
    }
    int i = (blockIdx.x * 256 + threadIdx.x) * 4;
    if (i >= n) return;
    float4 v = *(const float4*)&s[i];
    ushort4 o = { f2bf(v.x), f2bf(v.y), f2bf(v.z), f2bf(v.w) };
    *(ushort4*)&d[i] = o;
}

// ---------------------------------------------------------------------------
// QKV GEMM: minimum-2-phase DMA pipeline (R11). R12 adds F16OUT: the V
// projection is written as fp16 so attn can stage V via gload_lds16 directly
// into a ds_read_b64_tr_b16-ready layout and feed mfma_f16 with NO transpose
// pass (fp16 is strictly more precise than the old bf16 V path).
// ---------------------------------------------------------------------------
struct QkvSmem {
    ushort As[2][128][64];   // 2 x 16 KB
    ushort Bs[2][64][64];    // 2 x  8 KB
};

template<bool QSCALE, bool F16OUT>
__device__ __forceinline__ void gemm_qkv_body(QkvSmem& sm,
                                              const ushort* __restrict__ A,
                                              const ushort* __restrict__ W,
                                              const float* __restrict__ bias,
                                              const float* __restrict__ beta,
                                              ushort* __restrict__ C,
                                              int bx, int by)
{
    const int tid  = threadIdx.x;
    const int lane = tid & 63, w = tid >> 6;
    const int ln15 = lane & 15, quad = lane >> 4;
    const int wm = w >> 1, wn = w & 1;

    // DMA staging geometry: one gload_lds = 64 lanes x 16B = 8 rows of 128 B.
    // Wave w stages As rows w*32..w*32+31 (4 ops) + Bs rows w*16..+15 (2 ops).
    const int rl = lane >> 3, cl = lane & 7;
    const ushort* aRow[4];
#pragma unroll
    for (int i = 0; i < 4; ++i) {
        int row   = w * 32 + 8 * i + rl;
        int chunk = cl ^ ((row >> 1) & 7);              // inverse-swizzled src
        aRow[i] = A + (size_t)(by * 128 + row) * DM + chunk * 8;
    }
    const ushort* bRow[2];
#pragma unroll
    for (int i = 0; i < 2; ++i) {
        int row   = w * 16 + 8 * i + rl;
        int chunk = cl ^ ((row >> 1) & 7);
        bRow[i] = W + (size_t)(bx * 64 + row) * DM + chunk * 8;
    }

    const floatx4 zero = {0.f, 0.f, 0.f, 0.f};
    floatx4 acc[4][2];
#pragma unroll
    for (int i = 0; i < 4; ++i)
#pragma unroll
        for (int j = 0; j < 2; ++j) acc[i][j] = zero;

    // prologue: stage tile 0 into buffer 0
#pragma unroll
    for (int i = 0; i < 4; ++i) gload_lds16(aRow[i], &sm.As[0][w * 32 + 8 * i][0]);
#pragma unroll
    for (int i = 0; i < 2; ++i) gload_lds16(bRow[i], &sm.Bs[0][w * 16 + 8 * i][0]);
    __syncthreads();                                    // drains vmcnt -> buf0 ready

    const int rf = (ln15 >> 1) & 7;                     // frag-read swizzle key
#pragma unroll 2
    for (int t = 0; t < 16; ++t) {
        const int cur = t & 1, nxt = cur ^ 1;
        if (t < 15) {                                   // issue prefetch FIRST
            const int ko = (t + 1) * 64;
#pragma unroll
            for (int i = 0; i < 4; ++i) gload_lds16(aRow[i] + ko, &sm.As[nxt][w * 32 + 8 * i][0]);
#pragma unroll
            for (int i = 0; i < 2; ++i) gload_lds16(bRow[i] + ko, &sm.Bs[nxt][w * 16 + 8 * i][0]);
        }
#pragma unroll
        for (int s = 0; s < 2; ++s) {                   // two K=32 substeps
            short8 af[4], bf[2];
#pragma unroll
            for (int i = 0; i < 4; ++i)
                af[i] = *(const short8*)&sm.As[cur][wm * 64 + i * 16 + ln15][((s * 4 + quad) ^ rf) * 8];
#pragma unroll
            for (int j = 0; j < 2; ++j)
                bf[j] = *(const short8*)&sm.Bs[cur][wn * 32 + j * 16 + ln15][((s * 4 + quad) ^ rf) * 8];
#pragma unroll
            for (int i = 0; i < 4; ++i)
#pragma unroll
                for (int j = 0; j < 2; ++j)
                    acc[i][j] = __builtin_amdgcn_mfma_f32_16x16x32_bf16(af[i], bf[j], acc[i][j], 0, 0, 0);
        }
        __syncthreads();   // single barrier: drains vmcnt (prefetch done) +
                           // lgkm (tile-t reads done) -> next iter may write cur
    }

#pragma unroll
    for (int j = 0; j < 2; ++j) {
        const int col = bx * 64 + wn * 32 + j * 16 + ln15;
        const float b = bias[col];
        const float scale = QSCALE ? 0.125f * __expf(-beta[col >> 6]) : 1.0f;
#pragma unroll
        for (int i = 0; i < 4; ++i) {
            const int row0 = by * 128 + wm * 64 + i * 16 + quad * 4;
#pragma unroll
            for (int rg = 0; rg < 4; ++rg) {
                float vv = (acc[i][j][rg] + b) * scale;
                C[(size_t)(row0 + rg) * DM + col] = F16OUT ? f2h(vv) : f2bf(vv);
            }
        }
    }
}

// grid (16, 24, 3): z selects Q/K/V. 1152 blocks; 48 KB LDS -> 3 blocks/CU.
__global__ __launch_bounds__(256, 3) void qkv_kernel(
    const ushort* __restrict__ xb,
    const ushort* __restrict__ Wqb, const float* __restrict__ bq,
    const ushort* __restrict__ Wkb, const float* __restrict__ bk,
    const ushort* __restrict__ Wvb, const float* __restrict__ bv,
    const float* __restrict__ beta,
    ushort* __restrict__ q, ushort* __restrict__ k, ushort* __restrict__ v)
{
    __shared__ QkvSmem sm;                     // single allocation, shared by
    const int z = blockIdx.z;                  // ALL instantiations below
    const ushort* W = (z == 0) ? Wqb : (z == 1) ? Wkb : Wvb;
    const float*  b = (z == 0) ? bq  : (z == 1) ? bk  : bv;
    ushort*       C = (z == 0) ? q   : (z == 1) ? k   : v;
    if (z == 0)
        gemm_qkv_body<true , false>(sm, xb, W, b, beta, C, blockIdx.x, blockIdx.y);
    else if (z == 1)
        gemm_qkv_body<false, false>(sm, xb, W, b, nullptr, C, blockIdx.x, blockIdx.y);
    else
        gemm_qkv_body<false, true >(sm, xb, W, b, nullptr, C, blockIdx.x, blockIdx.y);
}

// ---------------------------------------------------------------------------
// Output GEMM: 64x64 tile, BK=64, grid 768 (3/CU). Minimum-2-phase DMA
// pipeline: dbuf LDS 32 KB, one barrier/iter, pre-swizzled gload_lds.
// ---------------------------------------------------------------------------
__global__ __launch_bounds__(256, 3) void out_kernel(
    const ushort* __restrict__ ctxb, const ushort* __restrict__ Wob,
    const float* __restrict__ bo, float* __restrict__ out)
{
    __shared__ ushort As[2][64][64];    // 16 KB
    __shared__ ushort Bs[2][64][64];    // 16 KB

    const int tid  = threadIdx.x;
    const int lane = tid & 63, w = tid >> 6;
    const int ln15 = lane & 15, quad = lane >> 4;
    const int wm = w >> 1, wn = w & 1;
    const int bx = blockIdx.x, by = blockIdx.y;

    // wave w stages As rows w*16..+15 (2 ops) and Bs rows w*16..+15 (2 ops)
    const int rl = lane >> 3, cl = lane & 7;
    const ushort* aRow[2]; const ushort* bRow[2];
#pragma unroll
    for (int i = 0; i < 2; ++i) {
        int row   = w * 16 + 8 * i + rl;
        int chunk = cl ^ ((row >> 1) & 7);
        aRow[i] = ctxb + (size_t)(by * 64 + row) * DM + chunk * 8;
        bRow[i] = Wob  + (size_t)(bx * 64 + row) * DM + chunk * 8;
    }

    const floatx4 zero = {0.f, 0.f, 0.f, 0.f};
    floatx4 acc[2][2];
#pragma unroll
    for (int i = 0; i < 2; ++i)
#pragma unroll
        for (int j = 0; j < 2; ++j) acc[i][j] = zero;

    // prologue
#pragma unroll
    for (int i = 0; i < 2; ++i) {
        gload_lds16(aRow[i], &As[0][w * 16 + 8 * i][0]);
        gload_lds16(bRow[i], &Bs[0][w * 16 + 8 * i][0]);
    }
    __syncthreads();

    const int rf = (ln15 >> 1) & 7;
#pragma unroll 2
    for (int t = 0; t < 16; ++t) {
        const int cur = t & 1, nxt = cur ^ 1;
        if (t < 15) {
            const int ko = (t + 1) * 64;
#pragma unroll
            for (int i = 0; i < 2; ++i) {
                gload_lds16(aRow[i] + ko, &As[nxt][w * 16 + 8 * i][0]);
                gload_lds16(bRow[i] + ko, &Bs[nxt][w * 16 + 8 * i][0]);
            }
        }
#pragma unroll
        for (int s = 0; s < 2; ++s) {
            short8 af[2], bf[2];
#pragma unroll
            for (int i = 0; i < 2; ++i)
                af[i] = *(const short8*)&As[cur][wm * 32 + i * 16 + ln15][((s * 4 + quad) ^ rf) * 8];
#pragma unroll
            for (int j = 0; j < 2; ++j)
                bf[j] = *(const short8*)&Bs[cur][wn * 32 + j * 16 + ln15][((s * 4 + quad) ^ rf) * 8];
#pragma unroll
            for (int i = 0; i < 2; ++i)
#pragma unroll
                for (int j = 0; j < 2; ++j)
                    acc[i][j] = __builtin_amdgcn_mfma_f32_16x16x32_bf16(af[i], bf[j], acc[i][j], 0, 0, 0);
        }
        __syncthreads();
    }

#pragma unroll
    for (int j = 0; j < 2; ++j) {
        const int col = bx * 64 + wn * 32 + j * 16 + ln15;
        const float b = bo[col];
#pragma unroll
        for (int i = 0; i < 2; ++i) {
            const int row0 = by * 64 + wm * 32 + i * 16 + quad * 4;
#pragma unroll
            for (int rg = 0; rg < 4; ++rg)
                out[(size_t)(row0 + rg) * DM + col] = acc[i][j][rg] + b;
        }
    }
}

// ---------------------------------------------------------------------------
// MFMA attention, R12: V transpose pass DELETED.
//  - V (fp16, from qkv) is staged AFTER barrier 2 (Vs aliases Ks) via
//    gload_lds16 directly into a tr-read-ready subtiled layout:
//      tile T=(kc*4+dt)*2+p (512 B) = 4 quad-groups x 4 keys x 16 dims,
//      flat(T,q,jj,e) = T*256 + q*64 + jj*16 + e,
//      key = kc*32 + q*8 + p*4 + jj, dim = dt*16 + e.
//    Each 16-B LDS chunk = 8 consecutive dims of ONE key -> per-lane global
//    source permutation realizes the layout at zero shuffle cost (m173).
//  - PV reads B-frags with ds_read_b64_tr_b16 (vaddr = base + lane*8: lane
//    receives column lane&15 of its 16-lane group's [4][16] tile, m162):
//    frag[0..3] = p=0 tile, frag[4..7] = p=1 tile.
//  - DMA latency hides under softmax; barrier 3 drains vmcnt.
//  Removes per-thread: 48 scalar ds_writes, ~150 VALU converts, 6 early
//  global vector loads (~48 VGPRs).
// ---------------------------------------------------------------------------
struct AttnSmem {
    union {
        ushort Ks[192 * 64];        // [key][dg] ; dg holds dims 8*(dg^(key&7))
        ushort Vs[48 * 256];        // 48 tr-read tiles (fp16), see above
    } u;
    float S[32][195];
    float Rsum[32];
};

__global__ __launch_bounds__(256) void attn_kernel(
    const ushort* __restrict__ q, const ushort* __restrict__ k,
    const ushort* __restrict__ v, ushort* __restrict__ ctx)
{
    __shared__ AttnSmem sm;

    const int tid  = threadIdx.x;
    const int lane = tid & 63, w = tid >> 6;
    const int ln15 = lane & 15, quad = lane >> 4;
    const int t0   = blockIdx.x * 32;
    const int r    = blockIdx.y;
    const int h    = blockIdx.z;
    const int hoff = h * DH;

    // ---- stage K (192 keys x 64 dims) via glds, 6 ops/wave -----------------
    {
        const int kr = lane >> 3;                   // key-in-op 0..7
        const int swz = ((lane & 7) ^ kr) * 8;      // XOR swizzle on global dim
#pragma unroll
        for (int ci = w * 6; ci < w * 6 + 6; ++ci) {
            int key = ci * 8 + kr;
            long grow = 4L * (t0 - 160 + key) + r;  // may be negative -> q buffer
            gload_lds16(k + grow * DM + hoff + swz, &sm.u.Ks[ci * 512]);
        }
    }

    // ---- Q A-frags direct from global (wave w owns qtile w>>1) -------------
    const int qt = w >> 1;
    short8 qf0, qf1;
    {
        int qrow = qt * 16 + ln15;
        const ushort* gq = q + (4L * (t0 + qrow) + r) * DM + hoff + quad * 8;
        qf0 = *(const short8*)gq;
        qf1 = *(const short8*)(gq + 32);
    }

    __syncthreads();   // barrier 1: Ks staged (vmcnt drained by sync)

    // ---- QK^T: wave w -> qtile w>>1, ktiles (w&1)*6 .. +5 ------------------
    {
        const floatx4 zero = {0.f, 0.f, 0.f, 0.f};
        const int kt0 = (w & 1) * 6;
        const int lb  = ln15 & 7;
#pragma unroll
        for (int kk2 = 0; kk2 < 6; ++kk2) {
            const int kt  = kt0 + kk2;
            const int key = kt * 16 + ln15;
            short8 b0 = *(const short8*)&sm.u.Ks[key * 64 + ((quad ^ lb) << 3)];
            short8 b1 = *(const short8*)&sm.u.Ks[key * 64 + (((4 + quad) ^ lb) << 3)];
            floatx4 acc = zero;
            acc = __builtin_amdgcn_mfma_f32_16x16x32_bf16(qf0, b0, acc, 0, 0, 0);
            acc = __builtin_amdgcn_mfma_f32_16x16x32_bf16(qf1, b1, acc, 0, 0, 0);
            const int tp = t0 - 160 + key;          // key slot time
#pragma unroll
            for (int rg = 0; rg < 4; ++rg) {
                int qrow = qt * 16 + quad * 4 + rg;
                int tq = t0 + qrow;
                bool ok = (tp >= 0) && (tp <= tq) && (tp > tq - WIN);
                sm.S[qrow][key] = ok ? acc[rg] : -1e30f;
            }
        }
    }

    __syncthreads();   // barrier 2: S complete, Ks reads done (Vs may alias)

    // ---- stage V (fp16) into tr-read layout via glds, 6 ops/wave -----------
    {
#pragma unroll
        for (int i = 0; i < 6; ++i) {
            const int o  = w * 6 + i;               // op 0..23
            const int c  = o * 64 + lane;           // 16-B chunk index
            const int hh = c & 1, jj = (c >> 1) & 3, qq = (c >> 3) & 3;
            const int T  = c >> 5;
            const int p  = T & 1, dtt = (T >> 1) & 3, kc = T >> 3;
            const int key = kc * 32 + qq * 8 + p * 4 + jj;
            const int dim = dtt * 16 + hh * 8;
            long grow = 4L * (t0 - 160 + key) + r;  // may be negative -> masked
            gload_lds16(v + grow * DM + hoff + dim, &sm.u.Vs[o * 512]);
        }
    }

    // ---- softmax: 8 threads/row, stride-8 slot ownership -------------------
    // (V DMA latency hides under this; barrier 3 drains vmcnt.)
    {
        const int sq = tid >> 3, part = tid & 7;
        float m = -1e30f;
#pragma unroll
        for (int j = 0; j < 24; ++j) m = fmaxf(m, sm.S[sq][part + 8 * j]);
#pragma unroll
        for (int o = 1; o < 8; o <<= 1) m = fmaxf(m, __shfl_xor(m, o));
        float sum = 0.f;
#pragma unroll
        for (int j = 0; j < 24; ++j) {
            int ks = part + 8 * j;
            float e = __expf(sm.S[sq][ks] - m);
            sm.S[sq][ks] = e;
            sum += e;
        }
#pragma unroll
        for (int o = 1; o < 8; o <<= 1) sum += __shfl_xor(sum, o);
        if (part == 0) sm.Rsum[sq] = 1.0f / sum;
    }

    __syncthreads();   // barrier 3: Vs + P(S) + Rsum ready (vmcnt drained)

    // ---- PV: wave w -> qtile w&1, dtiles (w>>1)*2 .. +1 --------------------
    {
        const floatx4 zero = {0.f, 0.f, 0.f, 0.f};
        const int qtp = w & 1, dh = w >> 1;
        floatx4 o0 = zero, o1 = zero;
        // byte addr: tile(kc,dt,p) at kc*4096 + dt*1024 + p*512; dt0 = dh*2.
        const unsigned vbase =
            (unsigned)(size_t)(__attribute__((address_space(3))) ushort*)&sm.u.Vs[0]
            + lane * 8 + dh * 2048;
#pragma unroll
        for (int kc = 0; kc < 6; ++kc) {
            const float* ps = &sm.S[qtp * 16 + ln15][kc * 32 + quad * 8];
            half8 pa;
#pragma unroll
            for (int u = 0; u < 8; ++u) pa[u] = (_Float16)ps[u];
            half4 a0, a1, b0, b1;
            asm volatile(
                "ds_read_b64_tr_b16 %0, %4\n\t"
                "ds_read_b64_tr_b16 %1, %4 offset:512\n\t"
                "ds_read_b64_tr_b16 %2, %4 offset:1024\n\t"
                "ds_read_b64_tr_b16 %3, %4 offset:1536\n\t"
                "s_waitcnt lgkmcnt(0)"
                : "=&v"(a0), "=&v"(a1), "=&v"(b0), "=&v"(b1)
                : "v"(vbase + kc * 4096));
            __builtin_amdgcn_sched_barrier(0);      // rule #18 fence
            half8 vb0 = __builtin_shufflevector(a0, a1, 0, 1, 2, 3, 4, 5, 6, 7);
            half8 vb1 = __builtin_shufflevector(b0, b1, 0, 1, 2, 3, 4, 5, 6, 7);
            o0 = __builtin_amdgcn_mfma_f32_16x16x32_f16(pa, vb0, o0, 0, 0, 0);
            o1 = __builtin_amdgcn_mfma_f32_16x16x32_f16(pa, vb1, o1, 0, 0, 0);
        }
#pragma unroll
        for (int rg = 0; rg < 4; ++rg) {
            int qrow = qtp * 16 + quad * 4 + rg;
            float rs = sm.Rsum[qrow];
            long orow = 4L * (t0 + qrow) + r;
            ushort* cp = ctx + orow * DM + hoff + dh * 32 + ln15;
            cp[0]  = f2bf(o0[rg] * rs);
            cp[16] = f2bf(o1[rg] * rs);
        }
    }
}

// ---------------------------------------------------------------------------
// ws layout: q, k, ctx bf16; v fp16; x, Wq, Wk, Wv, Wo bf16.
// ---------------------------------------------------------------------------
extern "C" void kernel_launch(void* const* d_in, const int* in_sizes, int n_in,
                              void* d_out, int out_size, void* d_ws, size_t ws_size,
                              hipStream_t stream)
{
    const float* x    = (const float*)d_in[0];
    const float* beta = (const float*)d_in[1];
    const float* Wq   = (const float*)d_in[2];
    const float* bq   = (const float*)d_in[3];
    const float* Wk   = (const float*)d_in[4];
    const float* bk   = (const float*)d_in[5];
    const float* Wv   = (const float*)d_in[6];
    const float* bv   = (const float*)d_in[7];
    const float* Wo   = (const float*)d_in[8];
    const float* bo   = (const float*)d_in[9];

    ushort* qb   = (ushort*)d_ws;
    ushort* kb   = qb   + (size_t)SEQ * DM;
    ushort* vb   = kb   + (size_t)SEQ * DM;
    ushort* ctxb = vb   + (size_t)SEQ * DM;
    ushort* xb   = ctxb + (size_t)SEQ * DM;
    ushort* Wqb  = xb   + (size_t)SEQ * DM;
    ushort* Wkb  = Wqb  + (size_t)DM * DM;
    ushort* Wvb  = Wkb  + (size_t)DM * DM;
    ushort* Wob  = Wvb  + (size_t)DM * DM;
    float*  out  = (float*)d_out;

    dim3 gcv(SEQ * DM / 4 / 256, 5);
    convert_kernel<<<gcv, 256, 0, stream>>>(x, Wq, Wk, Wv, Wo, xb, Wqb, Wkb, Wvb, Wob);

    dim3 gqkv(DM / 64, SEQ / 128, 3);           // (16, 24, 3) = 1152 blocks
    qkv_kernel<<<gqkv, 256, 0, stream>>>(xb, Wqb, bq, Wkb, bk, Wvb, bv, beta, qb, kb, vb);

    dim3 gattn(TSUB / 32, DIL, NH);             // (24, 4, 16) = 1536 blocks
    attn_kernel<<<gattn, 256, 0, stream>>>(qb, kb, vb, ctxb);

    dim3 gout(DM / 64, SEQ / 64);               // (16, 48) = 768 blocks
    out_kernel<<<gout, 256, 0, stream>>>(ctxb, Wob, bo, out);
}

// Round 4
// 150.316 us; speedup vs baseline: 1.1802x; 1.0182x over previous
//
#include <hip/hip_runtime.h>
#include <math.h>

#define SEQ   3072
#define DM    1024
#define NH    16
#define DH    64
#define WIN   128
#define DIL   4
#define TSUB  768      // SEQ / DIL

typedef __attribute__((ext_vector_type(8))) short    short8;   // 8 bf16
typedef __attribute__((ext_vector_type(8))) _Float16 half8;    // 8 fp16
typedef __attribute__((ext_vector_type(4))) _Float16 half4;    // 4 fp16 (64b)
typedef __attribute__((ext_vector_type(4))) float    floatx4;  // MFMA C/D

__device__ __forceinline__ float bf2f(unsigned short u) {
    return __uint_as_float(((unsigned)u) << 16);
}
__device__ __forceinline__ unsigned short f2bf(float f) {   // RNE, finite inputs
    unsigned u = __float_as_uint(f);
    return (unsigned short)((u + 0x7FFFu + ((u >> 16) & 1u)) >> 16);
}
__device__ __forceinline__ unsigned short f2h(float f) {
    _Float16 h = (_Float16)f;
    return __builtin_bit_cast(unsigned short, h);
}

// async global->LDS, 16B/lane. LDS dest is WAVE-UNIFORM base + lane*16
// (hardware adds the lane offset); global src is per-lane.
__device__ __forceinline__ void gload_lds16(const void* g, void* l) {
    __builtin_amdgcn_global_load_lds(
        (const __attribute__((address_space(1))) void*)g,
        (__attribute__((address_space(3))) void*)l, 16, 0, 0);
}

// ---------------------------------------------------------------------------
// fp32 -> bf16 conversion (R8: fp32 inputs in the GEMM loop double FETCH and
// cost 33 us; convert once, read bf16).
// ---------------------------------------------------------------------------
__global__ __launch_bounds__(256) void convert_kernel(
    const float* __restrict__ x,  const float* __restrict__ Wq,
    const float* __restrict__ Wk, const float* __restrict__ Wv,
    const float* __restrict__ Wo,
    ushort* __restrict__ xb,  ushort* __restrict__ Wqb,
    ushort* __restrict__ Wkb, ushort* __restrict__ Wvb,
    ushort* __restrict__ Wob)
{
    const float* s; ushort* d; int n;
    switch (blockIdx.y) {
        case 0: s = x;  d = xb;  n = SEQ * DM; break;
        case 1: s = Wq; d = Wqb; n = DM * DM;  break;
        case 2: s = Wk; d = Wkb; n = DM * DM;  break;
        case 3: s = Wv; d = Wvb; n = DM * DM;  break;
        default: s = Wo; d = Wob; n = DM * DM; break;
    }
    int i = (blockIdx.x * 256 + threadIdx.x) * 4;
    if (i >= n) return;
    float4 v = *(const float4*)&s[i];
    ushort4 o = { f2bf(v.x), f2bf(v.y), f2bf(v.z), f2bf(v.w) };
    *(ushort4*)&d[i] = o;
}

// ---------------------------------------------------------------------------
// QKV GEMM, R13: counted-vmcnt two-barrier K-loop (T3/T4 recipe).
// R12's single __syncthreads per iter implied s_waitcnt vmcnt(0) right after
// the 6 prefetch loads were issued -> full ~500cy latency exposed per iter
// (drain-bound, not pipe-bound: per-CU LDS+MFMA work is only ~430cy/iter).
// Now: issue prefetch -> s_waitcnt vmcnt(6) (waits ONLY the oldest 6 = this
// tile's loads; prefetch stays in flight across compute) -> raw s_barrier ->
// compute -> lgkmcnt(0) + s_barrier (reads retired, buffer reusable).
// Count = LOADS_PER_TILE x tiles-in-flight = 6 x 1. Last iter: vmcnt(0).
// Epilogue bias/beta are PRELOADED + forced resident before the prologue so
// no stray VMEM op can corrupt the vmcnt arithmetic inside the loop.
// ---------------------------------------------------------------------------
struct QkvSmem {
    ushort As[2][128][64];   // 2 x 16 KB
    ushort Bs[2][64][64];    // 2 x  8 KB
};

template<bool QSCALE, bool F16OUT>
__device__ __forceinline__ void gemm_qkv_body(QkvSmem& sm,
                                              const ushort* __restrict__ A,
                                              const ushort* __restrict__ W,
                                              const float* __restrict__ bias,
                                              const float* __restrict__ beta,
                                              ushort* __restrict__ C,
                                              int bx, int by)
{
    const int tid  = threadIdx.x;
    const int lane = tid & 63, w = tid >> 6;
    const int ln15 = lane & 15, quad = lane >> 4;
    const int wm = w >> 1, wn = w & 1;

    // DMA staging geometry: one gload_lds = 64 lanes x 16B = 8 rows of 128 B.
    // Wave w stages As rows w*32..w*32+31 (4 ops) + Bs rows w*16..+15 (2 ops).
    const int rl = lane >> 3, cl = lane & 7;
    const ushort* aRow[4];
#pragma unroll
    for (int i = 0; i < 4; ++i) {
        int row   = w * 32 + 8 * i + rl;
        int chunk = cl ^ ((row >> 1) & 7);              // inverse-swizzled src
        aRow[i] = A + (size_t)(by * 128 + row) * DM + chunk * 8;
    }
    const ushort* bRow[2];
#pragma unroll
    for (int i = 0; i < 2; ++i) {
        int row   = w * 16 + 8 * i + rl;
        int chunk = cl ^ ((row >> 1) & 7);
        bRow[i] = W + (size_t)(bx * 64 + row) * DM + chunk * 8;
    }

    // ---- preload epilogue scalars; force resident (vmcnt hygiene) ----------
    const int col0 = bx * 64 + wn * 32 + ln15;          // j=0 col
    float eb0 = bias[col0];
    float eb1 = bias[col0 + 16];                        // j=1 col
    float escale = QSCALE ? 0.125f * __expf(-beta[bx]) : 1.0f;  // head = col>>6 = bx
    asm volatile("" : "+v"(eb0), "+v"(eb1), "+v"(escale));

    const floatx4 zero = {0.f, 0.f, 0.f, 0.f};
    floatx4 acc[4][2];
#pragma unroll
    for (int i = 0; i < 4; ++i)
#pragma unroll
        for (int j = 0; j < 2; ++j) acc[i][j] = zero;

    // prologue: stage tile 0 into buffer 0 (no barrier; loop iter 0 waits)
#pragma unroll
    for (int i = 0; i < 4; ++i) gload_lds16(aRow[i], &sm.As[0][w * 32 + 8 * i][0]);
#pragma unroll
    for (int i = 0; i < 2; ++i) gload_lds16(bRow[i], &sm.Bs[0][w * 16 + 8 * i][0]);

    const int rf = (ln15 >> 1) & 7;                     // frag-read swizzle key
#pragma unroll 2
    for (int t = 0; t < 16; ++t) {
        const int cur = t & 1, nxt = cur ^ 1;
        if (t < 15) {                                   // issue prefetch FIRST
            const int ko = (t + 1) * 64;
#pragma unroll
            for (int i = 0; i < 4; ++i) gload_lds16(aRow[i] + ko, &sm.As[nxt][w * 32 + 8 * i][0]);
#pragma unroll
            for (int i = 0; i < 2; ++i) gload_lds16(bRow[i] + ko, &sm.Bs[nxt][w * 16 + 8 * i][0]);
            __builtin_amdgcn_sched_barrier(0);
            asm volatile("s_waitcnt vmcnt(6)" ::: "memory");  // oldest 6 = tile t
        } else {
            __builtin_amdgcn_sched_barrier(0);
            asm volatile("s_waitcnt vmcnt(0)" ::: "memory");  // last tile
        }
        __builtin_amdgcn_sched_barrier(0);
        __builtin_amdgcn_s_barrier();                   // all waves: tile t resident
#pragma unroll
        for (int s = 0; s < 2; ++s) {                   // two K=32 substeps
            short8 af[4], bf[2];
#pragma unroll
            for (int i = 0; i < 4; ++i)
                af[i] = *(const short8*)&sm.As[cur][wm * 64 + i * 16 + ln15][((s * 4 + quad) ^ rf) * 8];
#pragma unroll
            for (int j = 0; j < 2; ++j)
                bf[j] = *(const short8*)&sm.Bs[cur][wn * 32 + j * 16 + ln15][((s * 4 + quad) ^ rf) * 8];
#pragma unroll
            for (int i = 0; i < 4; ++i)
#pragma unroll
                for (int j = 0; j < 2; ++j)
                    acc[i][j] = __builtin_amdgcn_mfma_f32_16x16x32_bf16(af[i], bf[j], acc[i][j], 0, 0, 0);
        }
        asm volatile("s_waitcnt lgkmcnt(0)" ::: "memory");
        __builtin_amdgcn_sched_barrier(0);
        __builtin_amdgcn_s_barrier();                   // all waves: reads done
    }

#pragma unroll
    for (int j = 0; j < 2; ++j) {
        const int col = col0 + j * 16;
        const float b = j ? eb1 : eb0;
#pragma unroll
        for (int i = 0; i < 4; ++i) {
            const int row0 = by * 128 + wm * 64 + i * 16 + quad * 4;
#pragma unroll
            for (int rg = 0; rg < 4; ++rg) {
                float vv = (acc[i][j][rg] + b) * escale;
                C[(size_t)(row0 + rg) * DM + col] = F16OUT ? f2h(vv) : f2bf(vv);
            }
        }
    }
}

// grid (16, 24, 3): z selects Q/K/V. 1152 blocks; 48 KB LDS -> 3 blocks/CU.
__global__ __launch_bounds__(256, 3) void qkv_kernel(
    const ushort* __restrict__ xb,
    const ushort* __restrict__ Wqb, const float* __restrict__ bq,
    const ushort* __restrict__ Wkb, const float* __restrict__ bk,
    const ushort* __restrict__ Wvb, const float* __restrict__ bv,
    const float* __restrict__ beta,
    ushort* __restrict__ q, ushort* __restrict__ k, ushort* __restrict__ v)
{
    __shared__ QkvSmem sm;                     // single allocation, shared by
    const int z = blockIdx.z;                  // ALL instantiations below
    const ushort* W = (z == 0) ? Wqb : (z == 1) ? Wkb : Wvb;
    const float*  b = (z == 0) ? bq  : (z == 1) ? bk  : bv;
    ushort*       C = (z == 0) ? q   : (z == 1) ? k   : v;
    if (z == 0)
        gemm_qkv_body<true , false>(sm, xb, W, b, beta, C, blockIdx.x, blockIdx.y);
    else if (z == 1)
        gemm_qkv_body<false, false>(sm, xb, W, b, nullptr, C, blockIdx.x, blockIdx.y);
    else
        gemm_qkv_body<false, true >(sm, xb, W, b, nullptr, C, blockIdx.x, blockIdx.y);
}

// ---------------------------------------------------------------------------
// Output GEMM: 64x64 tile, BK=64, grid 768 (3/CU). Same counted-vmcnt
// two-barrier loop; LOADS_PER_TILE = 4 -> steady-state wait vmcnt(4).
// ---------------------------------------------------------------------------
__global__ __launch_bounds__(256, 3) void out_kernel(
    const ushort* __restrict__ ctxb, const ushort* __restrict__ Wob,
    const float* __restrict__ bo, float* __restrict__ out)
{
    __shared__ ushort As[2][64][64];    // 16 KB
    __shared__ ushort Bs[2][64][64];    // 16 KB

    const int tid  = threadIdx.x;
    const int lane = tid & 63, w = tid >> 6;
    const int ln15 = lane & 15, quad = lane >> 4;
    const int wm = w >> 1, wn = w & 1;
    const int bx = blockIdx.x, by = blockIdx.y;

    // wave w stages As rows w*16..+15 (2 ops) and Bs rows w*16..+15 (2 ops)
    const int rl = lane >> 3, cl = lane & 7;
    const ushort* aRow[2]; const ushort* bRow[2];
#pragma unroll
    for (int i = 0; i < 2; ++i) {
        int row   = w * 16 + 8 * i + rl;
        int chunk = cl ^ ((row >> 1) & 7);
        aRow[i] = ctxb + (size_t)(by * 64 + row) * DM + chunk * 8;
        bRow[i] = Wob  + (size_t)(bx * 64 + row) * DM + chunk * 8;
    }

    // preload epilogue scalars; force resident (vmcnt hygiene)
    const int col0 = bx * 64 + wn * 32 + ln15;
    float eb0 = bo[col0];
    float eb1 = bo[col0 + 16];
    asm volatile("" : "+v"(eb0), "+v"(eb1));

    const floatx4 zero = {0.f, 0.f, 0.f, 0.f};
    floatx4 acc[2][2];
#pragma unroll
    for (int i = 0; i < 2; ++i)
#pragma unroll
        for (int j = 0; j < 2; ++j) acc[i][j] = zero;

    // prologue (no barrier; loop iter 0 waits)
#pragma unroll
    for (int i = 0; i < 2; ++i) {
        gload_lds16(aRow[i], &As[0][w * 16 + 8 * i][0]);
        gload_lds16(bRow[i], &Bs[0][w * 16 + 8 * i][0]);
    }

    const int rf = (ln15 >> 1) & 7;
#pragma unroll 2
    for (int t = 0; t < 16; ++t) {
        const int cur = t & 1, nxt = cur ^ 1;
        if (t < 15) {
            const int ko = (t + 1) * 64;
#pragma unroll
            for (int i = 0; i < 2; ++i) {
                gload_lds16(aRow[i] + ko, &As[nxt][w * 16 + 8 * i][0]);
                gload_lds16(bRow[i] + ko, &Bs[nxt][w * 16 + 8 * i][0]);
            }
            __builtin_amdgcn_sched_barrier(0);
            asm volatile("s_waitcnt vmcnt(4)" ::: "memory");  // oldest 4 = tile t
        } else {
            __builtin_amdgcn_sched_barrier(0);
            asm volatile("s_waitcnt vmcnt(0)" ::: "memory");
        }
        __builtin_amdgcn_sched_barrier(0);
        __builtin_amdgcn_s_barrier();
#pragma unroll
        for (int s = 0; s < 2; ++s) {
            short8 af[2], bf[2];
#pragma unroll
            for (int i = 0; i < 2; ++i)
                af[i] = *(const short8*)&As[cur][wm * 32 + i * 16 + ln15][((s * 4 + quad) ^ rf) * 8];
#pragma unroll
            for (int j = 0; j < 2; ++j)
                bf[j] = *(const short8*)&Bs[cur][wn * 32 + j * 16 + ln15][((s * 4 + quad) ^ rf) * 8];
#pragma unroll
            for (int i = 0; i < 2; ++i)
#pragma unroll
                for (int j = 0; j < 2; ++j)
                    acc[i][j] = __builtin_amdgcn_mfma_f32_16x16x32_bf16(af[i], bf[j], acc[i][j], 0, 0, 0);
        }
        asm volatile("s_waitcnt lgkmcnt(0)" ::: "memory");
        __builtin_amdgcn_sched_barrier(0);
        __builtin_amdgcn_s_barrier();
    }

#pragma unroll
    for (int j = 0; j < 2; ++j) {
        const int col = col0 + j * 16;
        const float b = j ? eb1 : eb0;
#pragma unroll
        for (int i = 0; i < 2; ++i) {
            const int row0 = by * 64 + wm * 32 + i * 16 + quad * 4;
#pragma unroll
            for (int rg = 0; rg < 4; ++rg)
                out[(size_t)(row0 + rg) * DM + col] = acc[i][j][rg] + b;
        }
    }
}

// ---------------------------------------------------------------------------
// MFMA attention (R12 structure: V staged fp16 directly into tr-read layout,
// PV via ds_read_b64_tr_b16; no transpose pass). Unchanged this round.
// ---------------------------------------------------------------------------
struct AttnSmem {
    union {
        ushort Ks[192 * 64];        // [key][dg] ; dg holds dims 8*(dg^(key&7))
        ushort Vs[48 * 256];        // 48 tr-read tiles (fp16)
    } u;
    float S[32][195];
    float Rsum[32];
};

__global__ __launch_bounds__(256) void attn_kernel(
    const ushort* __restrict__ q, const ushort* __restrict__ k,
    const ushort* __restrict__ v, ushort* __restrict__ ctx)
{
    __shared__ AttnSmem sm;

    const int tid  = threadIdx.x;
    const int lane = tid & 63, w = tid >> 6;
    const int ln15 = lane & 15, quad = lane >> 4;
    const int t0   = blockIdx.x * 32;
    const int r    = blockIdx.y;
    const int h    = blockIdx.z;
    const int hoff = h * DH;

    // ---- stage K (192 keys x 64 dims) via glds, 6 ops/wave -----------------
    {
        const int kr = lane >> 3;                   // key-in-op 0..7
        const int swz = ((lane & 7) ^ kr) * 8;      // XOR swizzle on global dim
#pragma unroll
        for (int ci = w * 6; ci < w * 6 + 6; ++ci) {
            int key = ci * 8 + kr;
            long grow = 4L * (t0 - 160 + key) + r;  // may be negative -> q buffer
            gload_lds16(k + grow * DM + hoff + swz, &sm.u.Ks[ci * 512]);
        }
    }

    // ---- Q A-frags direct from global (wave w owns qtile w>>1) -------------
    const int qt = w >> 1;
    short8 qf0, qf1;
    {
        int qrow = qt * 16 + ln15;
        const ushort* gq = q + (4L * (t0 + qrow) + r) * DM + hoff + quad * 8;
        qf0 = *(const short8*)gq;
        qf1 = *(const short8*)(gq + 32);
    }

    __syncthreads();   // barrier 1: Ks staged (vmcnt drained by sync)

    // ---- QK^T: wave w -> qtile w>>1, ktiles (w&1)*6 .. +5 ------------------
    {
        const floatx4 zero = {0.f, 0.f, 0.f, 0.f};
        const int kt0 = (w & 1) * 6;
        const int lb  = ln15 & 7;
#pragma unroll
        for (int kk2 = 0; kk2 < 6; ++kk2) {
            const int kt  = kt0 + kk2;
            const int key = kt * 16 + ln15;
            short8 b0 = *(const short8*)&sm.u.Ks[key * 64 + ((quad ^ lb) << 3)];
            short8 b1 = *(const short8*)&sm.u.Ks[key * 64 + (((4 + quad) ^ lb) << 3)];
            floatx4 acc = zero;
            acc = __builtin_amdgcn_mfma_f32_16x16x32_bf16(qf0, b0, acc, 0, 0, 0);
            acc = __builtin_amdgcn_mfma_f32_16x16x32_bf16(qf1, b1, acc, 0, 0, 0);
            const int tp = t0 - 160 + key;          // key slot time
#pragma unroll
            for (int rg = 0; rg < 4; ++rg) {
                int qrow = qt * 16 + quad * 4 + rg;
                int tq = t0 + qrow;
                bool ok = (tp >= 0) && (tp <= tq) && (tp > tq - WIN);
                sm.S[qrow][key] = ok ? acc[rg] : -1e30f;
            }
        }
    }

    __syncthreads();   // barrier 2: S complete, Ks reads done (Vs may alias)

    // ---- stage V (fp16) into tr-read layout via glds, 6 ops/wave -----------
    {
#pragma unroll
        for (int i = 0; i < 6; ++i) {
            const int o  = w * 6 + i;               // op 0..23
            const int c  = o * 64 + lane;           // 16-B chunk index
            const int hh = c & 1, jj = (c >> 1) & 3, qq = (c >> 3) & 3;
            const int T  = c >> 5;
            const int p  = T & 1, dtt = (T >> 1) & 3, kc = T >> 3;
            const int key = kc * 32 + qq * 8 + p * 4 + jj;
            const int dim = dtt * 16 + hh * 8;
            long grow = 4L * (t0 - 160 + key) + r;  // may be negative -> masked
            gload_lds16(v + grow * DM + hoff + dim, &sm.u.Vs[o * 512]);
        }
    }

    // ---- softmax: 8 threads/row, stride-8 slot ownership -------------------
    // (V DMA latency hides under this; barrier 3 drains vmcnt.)
    {
        const int sq = tid >> 3, part = tid & 7;
        float m = -1e30f;
#pragma unroll
        for (int j = 0; j < 24; ++j) m = fmaxf(m, sm.S[sq][part + 8 * j]);
#pragma unroll
        for (int o = 1; o < 8; o <<= 1) m = fmaxf(m, __shfl_xor(m, o));
        float sum = 0.f;
#pragma unroll
        for (int j = 0; j < 24; ++j) {
            int ks = part + 8 * j;
            float e = __expf(sm.S[sq][ks] - m);
            sm.S[sq][ks] = e;
            sum += e;
        }
#pragma unroll
        for (int o = 1; o < 8; o <<= 1) sum += __shfl_xor(sum, o);
        if (part == 0) sm.Rsum[sq] = 1.0f / sum;
    }

    __syncthreads();   // barrier 3: Vs + P(S) + Rsum ready (vmcnt drained)

    // ---- PV: wave w -> qtile w&1, dtiles (w>>1)*2 .. +1 --------------------
    {
        const floatx4 zero = {0.f, 0.f, 0.f, 0.f};
        const int qtp = w & 1, dh = w >> 1;
        floatx4 o0 = zero, o1 = zero;
        // byte addr: tile(kc,dt,p) at kc*4096 + dt*1024 + p*512; dt0 = dh*2.
        const unsigned vbase =
            (unsigned)(size_t)(__attribute__((address_space(3))) ushort*)&sm.u.Vs[0]
            + lane * 8 + dh * 2048;
#pragma unroll
        for (int kc = 0; kc < 6; ++kc) {
            const float* ps = &sm.S[qtp * 16 + ln15][kc * 32 + quad * 8];
            half8 pa;
#pragma unroll
            for (int u = 0; u < 8; ++u) pa[u] = (_Float16)ps[u];
            half4 a0, a1, b0, b1;
            asm volatile(
                "ds_read_b64_tr_b16 %0, %4\n\t"
                "ds_read_b64_tr_b16 %1, %4 offset:512\n\t"
                "ds_read_b64_tr_b16 %2, %4 offset:1024\n\t"
                "ds_read_b64_tr_b16 %3, %4 offset:1536\n\t"
                "s_waitcnt lgkmcnt(0)"
                : "=&v"(a0), "=&v"(a1), "=&v"(b0), "=&v"(b1)
                : "v"(vbase + kc * 4096));
            __builtin_amdgcn_sched_barrier(0);      // rule #18 fence
            half8 vb0 = __builtin_shufflevector(a0, a1, 0, 1, 2, 3, 4, 5, 6, 7);
            half8 vb1 = __builtin_shufflevector(b0, b1, 0, 1, 2, 3, 4, 5, 6, 7);
            o0 = __builtin_amdgcn_mfma_f32_16x16x32_f16(pa, vb0, o0, 0, 0, 0);
            o1 = __builtin_amdgcn_mfma_f32_16x16x32_f16(pa, vb1, o1, 0, 0, 0);
        }
#pragma unroll
        for (int rg = 0; rg < 4; ++rg) {
            int qrow = qtp * 16 + quad * 4 + rg;
            float rs = sm.Rsum[qrow];
            long orow = 4L * (t0 + qrow) + r;
            ushort* cp = ctx + orow * DM + hoff + dh * 32 + ln15;
            cp[0]  = f2bf(o0[rg] * rs);
            cp[16] = f2bf(o1[rg] * rs);
        }
    }
}

// ---------------------------------------------------------------------------
// ws layout: q, k, ctx bf16; v fp16; x, Wq, Wk, Wv, Wo bf16.
// ---------------------------------------------------------------------------
extern "C" void kernel_launch(void* const* d_in, const int* in_sizes, int n_in,
                              void* d_out, int out_size, void* d_ws, size_t ws_size,
                              hipStream_t stream)
{
    const float* x    = (const float*)d_in[0];
    const float* beta = (const float*)d_in[1];
    const float* Wq   = (const float*)d_in[2];
    const float* bq   = (const float*)d_in[3];
    const float* Wk   = (const float*)d_in[4];
    const float* bk   = (const float*)d_in[5];
    const float* Wv   = (const float*)d_in[6];
    const float* bv   = (const float*)d_in[7];
    const float* Wo   = (const float*)d_in[8];
    const float* bo   = (const float*)d_in[9];

    ushort* qb   = (ushort*)d_ws;
    ushort* kb   = qb   + (size_t)SEQ * DM;
    ushort* vb   = kb   + (size_t)SEQ * DM;
    ushort* ctxb = vb   + (size_t)SEQ * DM;
    ushort* xb   = ctxb + (size_t)SEQ * DM;
    ushort* Wqb  = xb   + (size_t)SEQ * DM;
    ushort* Wkb  = Wqb  + (size_t)DM * DM;
    ushort* Wvb  = Wkb  + (size_t)DM * DM;
    ushort* Wob  = Wvb  + (size_t)DM * DM;
    float*  out  = (float*)d_out;

    dim3 gcv(SEQ * DM / 4 / 256, 5);
    convert_kernel<<<gcv, 256, 0, stream>>>(x, Wq, Wk, Wv, Wo, xb, Wqb, Wkb, Wvb, Wob);

    dim3 gqkv(DM / 64, SEQ / 128, 3);           // (16, 24, 3) = 1152 blocks
    qkv_kernel<<<gqkv, 256, 0, stream>>>(xb, Wqb, bq, Wkb, bk, Wvb, bv, beta, qb, kb, vb);

    dim3 gattn(TSUB / 32, DIL, NH);             // (24, 4, 16) = 1536 blocks
    attn_kernel<<<gattn, 256, 0, stream>>>(qb, kb, vb, ctxb);

    dim3 gout(DM / 64, SEQ / 64);               // (16, 48) = 768 blocks
    out_kernel<<<gout, 256, 0, stream>>>(ctxb, Wob, bo, out);
}

// Round 5
// 145.143 us; speedup vs baseline: 1.2223x; 1.0356x over previous
//
#include <hip/hip_runtime.h>
#include <math.h>

#define SEQ   3072
#define DM    1024
#define NH    16
#define DH    64
#define WIN   128
#define DIL   4
#define TSUB  768      // SEQ / DIL

typedef __attribute__((ext_vector_type(8))) short    short8;   // 8 bf16
typedef __attribute__((ext_vector_type(8))) _Float16 half8;    // 8 fp16
typedef __attribute__((ext_vector_type(4))) _Float16 half4;    // 4 fp16 (64b)
typedef __attribute__((ext_vector_type(4))) float    floatx4;  // MFMA C/D

__device__ __forceinline__ float bf2f(unsigned short u) {
    return __uint_as_float(((unsigned)u) << 16);
}
__device__ __forceinline__ unsigned short f2bf(float f) {   // RNE, finite inputs
    unsigned u = __float_as_uint(f);
    return (unsigned short)((u + 0x7FFFu + ((u >> 16) & 1u)) >> 16);
}
__device__ __forceinline__ unsigned short f2h(float f) {
    _Float16 h = (_Float16)f;
    return __builtin_bit_cast(unsigned short, h);
}

// async global->LDS, 16B/lane. LDS dest is WAVE-UNIFORM base + lane*16
// (hardware adds the lane offset); global src is per-lane.
__device__ __forceinline__ void gload_lds16(const void* g, void* l) {
    __builtin_amdgcn_global_load_lds(
        (const __attribute__((address_space(1))) void*)g,
        (__attribute__((address_space(3))) void*)l, 16, 0, 0);
}

// ---------------------------------------------------------------------------
// fp32 -> bf16 conversion (R8: fp32 inputs in the GEMM loop double FETCH and
// cost 33 us; convert once, read bf16).
// ---------------------------------------------------------------------------
__global__ __launch_bounds__(256) void convert_kernel(
    const float* __restrict__ x,  const float* __restrict__ Wq,
    const float* __restrict__ Wk, const float* __restrict__ Wv,
    const float* __restrict__ Wo,
    ushort* __restrict__ xb,  ushort* __restrict__ Wqb,
    ushort* __restrict__ Wkb, ushort* __restrict__ Wvb,
    ushort* __restrict__ Wob)
{
    const float* s; ushort* d; int n;
    switch (blockIdx.y) {
        case 0: s = x;  d = xb;  n = SEQ * DM; break;
        case 1: s = Wq; d = Wqb; n = DM * DM;  break;
        case 2: s = Wk; d = Wkb; n = DM * DM;  break;
        case 3: s = Wv; d = Wvb; n = DM * DM;  break;
        default: s = Wo; d = Wob; n = DM * DM; break;
    }
    int i = (blockIdx.x * 256 + threadIdx.x) * 4;
    if (i >= n) return;
    float4 v = *(const float4*)&s[i];
    ushort4 o = { f2bf(v.x), f2bf(v.y), f2bf(v.z), f2bf(v.w) };
    *(ushort4*)&d[i] = o;
}

// ---------------------------------------------------------------------------
// QKV GEMM, R14: counted-vmcnt two-barrier K-loop (R13) + XCD-aware swizzle.
// R13 post-mortem: counted vmcnt bought only ~3 us -> the loop was NOT
// drain-bound (resident waves already covered it, m114). New theory: L2/L3
// re-read BW. Default linear->XCD round-robin scatters same-A-panel blocks
// across all 8 XCDs: L1-miss traffic = 3z x (16bx x 6.29MB A + 24by x 2MB B)
// ~= 446 MB through L3 (~17 TB/s -> ~26 us). Swizzle: xcd = lid&7 owns 9
// contiguous A-panel groups G = z*24+by; the 16 bx blocks of a group share
// one 256-KB A-panel (L2-resident) and stream each B panel once; consecutive
// groups on an XCD mostly share z so B (2 MB) also stays L2-resident.
// Per-XCD L2 working set ~= 4 MB; L3 traffic drops to ~70 MB.
// ---------------------------------------------------------------------------
struct QkvSmem {
    ushort As[2][128][64];   // 2 x 16 KB
    ushort Bs[2][64][64];    // 2 x  8 KB
};

template<bool QSCALE, bool F16OUT>
__device__ __forceinline__ void gemm_qkv_body(QkvSmem& sm,
                                              const ushort* __restrict__ A,
                                              const ushort* __restrict__ W,
                                              const float* __restrict__ bias,
                                              const float* __restrict__ beta,
                                              ushort* __restrict__ C,
                                              int bx, int by)
{
    const int tid  = threadIdx.x;
    const int lane = tid & 63, w = tid >> 6;
    const int ln15 = lane & 15, quad = lane >> 4;
    const int wm = w >> 1, wn = w & 1;

    // DMA staging geometry: one gload_lds = 64 lanes x 16B = 8 rows of 128 B.
    // Wave w stages As rows w*32..w*32+31 (4 ops) + Bs rows w*16..+15 (2 ops).
    const int rl = lane >> 3, cl = lane & 7;
    const ushort* aRow[4];
#pragma unroll
    for (int i = 0; i < 4; ++i) {
        int row   = w * 32 + 8 * i + rl;
        int chunk = cl ^ ((row >> 1) & 7);              // inverse-swizzled src
        aRow[i] = A + (size_t)(by * 128 + row) * DM + chunk * 8;
    }
    const ushort* bRow[2];
#pragma unroll
    for (int i = 0; i < 2; ++i) {
        int row   = w * 16 + 8 * i + rl;
        int chunk = cl ^ ((row >> 1) & 7);
        bRow[i] = W + (size_t)(bx * 64 + row) * DM + chunk * 8;
    }

    // ---- preload epilogue scalars; force resident (vmcnt hygiene) ----------
    const int col0 = bx * 64 + wn * 32 + ln15;          // j=0 col
    float eb0 = bias[col0];
    float eb1 = bias[col0 + 16];                        // j=1 col
    float escale = QSCALE ? 0.125f * __expf(-beta[bx]) : 1.0f;  // head = col>>6 = bx
    asm volatile("" : "+v"(eb0), "+v"(eb1), "+v"(escale));

    const floatx4 zero = {0.f, 0.f, 0.f, 0.f};
    floatx4 acc[4][2];
#pragma unroll
    for (int i = 0; i < 4; ++i)
#pragma unroll
        for (int j = 0; j < 2; ++j) acc[i][j] = zero;

    // prologue: stage tile 0 into buffer 0 (no barrier; loop iter 0 waits)
#pragma unroll
    for (int i = 0; i < 4; ++i) gload_lds16(aRow[i], &sm.As[0][w * 32 + 8 * i][0]);
#pragma unroll
    for (int i = 0; i < 2; ++i) gload_lds16(bRow[i], &sm.Bs[0][w * 16 + 8 * i][0]);

    const int rf = (ln15 >> 1) & 7;                     // frag-read swizzle key
#pragma unroll 2
    for (int t = 0; t < 16; ++t) {
        const int cur = t & 1, nxt = cur ^ 1;
        if (t < 15) {                                   // issue prefetch FIRST
            const int ko = (t + 1) * 64;
#pragma unroll
            for (int i = 0; i < 4; ++i) gload_lds16(aRow[i] + ko, &sm.As[nxt][w * 32 + 8 * i][0]);
#pragma unroll
            for (int i = 0; i < 2; ++i) gload_lds16(bRow[i] + ko, &sm.Bs[nxt][w * 16 + 8 * i][0]);
            __builtin_amdgcn_sched_barrier(0);
            asm volatile("s_waitcnt vmcnt(6)" ::: "memory");  // oldest 6 = tile t
        } else {
            __builtin_amdgcn_sched_barrier(0);
            asm volatile("s_waitcnt vmcnt(0)" ::: "memory");  // last tile
        }
        __builtin_amdgcn_sched_barrier(0);
        __builtin_amdgcn_s_barrier();                   // all waves: tile t resident
#pragma unroll
        for (int s = 0; s < 2; ++s) {                   // two K=32 substeps
            short8 af[4], bf[2];
#pragma unroll
            for (int i = 0; i < 4; ++i)
                af[i] = *(const short8*)&sm.As[cur][wm * 64 + i * 16 + ln15][((s * 4 + quad) ^ rf) * 8];
#pragma unroll
            for (int j = 0; j < 2; ++j)
                bf[j] = *(const short8*)&sm.Bs[cur][wn * 32 + j * 16 + ln15][((s * 4 + quad) ^ rf) * 8];
#pragma unroll
            for (int i = 0; i < 4; ++i)
#pragma unroll
                for (int j = 0; j < 2; ++j)
                    acc[i][j] = __builtin_amdgcn_mfma_f32_16x16x32_bf16(af[i], bf[j], acc[i][j], 0, 0, 0);
        }
        asm volatile("s_waitcnt lgkmcnt(0)" ::: "memory");
        __builtin_amdgcn_sched_barrier(0);
        __builtin_amdgcn_s_barrier();                   // all waves: reads done
    }

#pragma unroll
    for (int j = 0; j < 2; ++j) {
        const int col = col0 + j * 16;
        const float b = j ? eb1 : eb0;
#pragma unroll
        for (int i = 0; i < 4; ++i) {
            const int row0 = by * 128 + wm * 64 + i * 16 + quad * 4;
#pragma unroll
            for (int rg = 0; rg < 4; ++rg) {
                float vv = (acc[i][j][rg] + b) * escale;
                C[(size_t)(row0 + rg) * DM + col] = F16OUT ? f2h(vv) : f2bf(vv);
            }
        }
    }
}

// 1-D grid 1152. XCD-aware decode: xcd = lid&7 (HW round-robin, m09);
// each XCD owns A-panel groups G = xcd*9 + s/16 (G = z*24+by), bx = s%16.
__global__ __launch_bounds__(256, 3) void qkv_kernel(
    const ushort* __restrict__ xb,
    const ushort* __restrict__ Wqb, const float* __restrict__ bq,
    const ushort* __restrict__ Wkb, const float* __restrict__ bk,
    const ushort* __restrict__ Wvb, const float* __restrict__ bv,
    const float* __restrict__ beta,
    ushort* __restrict__ q, ushort* __restrict__ k, ushort* __restrict__ v)
{
    __shared__ QkvSmem sm;                     // single allocation, shared by
    const int lid = blockIdx.x;                // ALL instantiations below
    const int xcd = lid & 7, s = lid >> 3;     // s: 0..143
    const int G   = xcd * 9 + (s >> 4);        // A-panel group 0..71
    const int by  = G % 24, z = G / 24;
    const int bx  = s & 15;
    const ushort* W = (z == 0) ? Wqb : (z == 1) ? Wkb : Wvb;
    const float*  b = (z == 0) ? bq  : (z == 1) ? bk  : bv;
    ushort*       C = (z == 0) ? q   : (z == 1) ? k   : v;
    if (z == 0)
        gemm_qkv_body<true , false>(sm, xb, W, b, beta, C, bx, by);
    else if (z == 1)
        gemm_qkv_body<false, false>(sm, xb, W, b, nullptr, C, bx, by);
    else
        gemm_qkv_body<false, true >(sm, xb, W, b, nullptr, C, bx, by);
}

// ---------------------------------------------------------------------------
// Output GEMM: 64x64 tile, BK=64, 1-D grid 768 (3/CU). Counted-vmcnt loop
// (LOADS_PER_TILE=4) + same XCD swizzle: 6 A-panel groups per XCD; per-XCD
// working set = 6 x 128KB ctx panels + 2MB Wo < 4MB L2.
// ---------------------------------------------------------------------------
__global__ __launch_bounds__(256, 3) void out_kernel(
    const ushort* __restrict__ ctxb, const ushort* __restrict__ Wob,
    const float* __restrict__ bo, float* __restrict__ out)
{
    __shared__ ushort As[2][64][64];    // 16 KB
    __shared__ ushort Bs[2][64][64];    // 16 KB

    const int tid  = threadIdx.x;
    const int lane = tid & 63, w = tid >> 6;
    const int ln15 = lane & 15, quad = lane >> 4;
    const int wm = w >> 1, wn = w & 1;

    const int lid = blockIdx.x;
    const int xcd = lid & 7, s0 = lid >> 3;    // s0: 0..95
    const int by  = xcd * 6 + (s0 >> 4);       // A-panel group 0..47
    const int bx  = s0 & 15;

    // wave w stages As rows w*16..+15 (2 ops) and Bs rows w*16..+15 (2 ops)
    const int rl = lane >> 3, cl = lane & 7;
    const ushort* aRow[2]; const ushort* bRow[2];
#pragma unroll
    for (int i = 0; i < 2; ++i) {
        int row   = w * 16 + 8 * i + rl;
        int chunk = cl ^ ((row >> 1) & 7);
        aRow[i] = ctxb + (size_t)(by * 64 + row) * DM + chunk * 8;
        bRow[i] = Wob  + (size_t)(bx * 64 + row) * DM + chunk * 8;
    }

    // preload epilogue scalars; force resident (vmcnt hygiene)
    const int col0 = bx * 64 + wn * 32 + ln15;
    float eb0 = bo[col0];
    float eb1 = bo[col0 + 16];
    asm volatile("" : "+v"(eb0), "+v"(eb1));

    const floatx4 zero = {0.f, 0.f, 0.f, 0.f};
    floatx4 acc[2][2];
#pragma unroll
    for (int i = 0; i < 2; ++i)
#pragma unroll
        for (int j = 0; j < 2; ++j) acc[i][j] = zero;

    // prologue (no barrier; loop iter 0 waits)
#pragma unroll
    for (int i = 0; i < 2; ++i) {
        gload_lds16(aRow[i], &As[0][w * 16 + 8 * i][0]);
        gload_lds16(bRow[i], &Bs[0][w * 16 + 8 * i][0]);
    }

    const int rf = (ln15 >> 1) & 7;
#pragma unroll 2
    for (int t = 0; t < 16; ++t) {
        const int cur = t & 1, nxt = cur ^ 1;
        if (t < 15) {
            const int ko = (t + 1) * 64;
#pragma unroll
            for (int i = 0; i < 2; ++i) {
                gload_lds16(aRow[i] + ko, &As[nxt][w * 16 + 8 * i][0]);
                gload_lds16(bRow[i] + ko, &Bs[nxt][w * 16 + 8 * i][0]);
            }
            __builtin_amdgcn_sched_barrier(0);
            asm volatile("s_waitcnt vmcnt(4)" ::: "memory");  // oldest 4 = tile t
        } else {
            __builtin_amdgcn_sched_barrier(0);
            asm volatile("s_waitcnt vmcnt(0)" ::: "memory");
        }
        __builtin_amdgcn_sched_barrier(0);
        __builtin_amdgcn_s_barrier();
#pragma unroll
        for (int s = 0; s < 2; ++s) {
            short8 af[2], bf[2];
#pragma unroll
            for (int i = 0; i < 2; ++i)
                af[i] = *(const short8*)&As[cur][wm * 32 + i * 16 + ln15][((s * 4 + quad) ^ rf) * 8];
#pragma unroll
            for (int j = 0; j < 2; ++j)
                bf[j] = *(const short8*)&Bs[cur][wn * 32 + j * 16 + ln15][((s * 4 + quad) ^ rf) * 8];
#pragma unroll
            for (int i = 0; i < 2; ++i)
#pragma unroll
                for (int j = 0; j < 2; ++j)
                    acc[i][j] = __builtin_amdgcn_mfma_f32_16x16x32_bf16(af[i], bf[j], acc[i][j], 0, 0, 0);
        }
        asm volatile("s_waitcnt lgkmcnt(0)" ::: "memory");
        __builtin_amdgcn_sched_barrier(0);
        __builtin_amdgcn_s_barrier();
    }

#pragma unroll
    for (int j = 0; j < 2; ++j) {
        const int col = col0 + j * 16;
        const float b = j ? eb1 : eb0;
#pragma unroll
        for (int i = 0; i < 2; ++i) {
            const int row0 = by * 64 + wm * 32 + i * 16 + quad * 4;
#pragma unroll
            for (int rg = 0; rg < 4; ++rg)
                out[(size_t)(row0 + rg) * DM + col] = acc[i][j][rg] + b;
        }
    }
}

// ---------------------------------------------------------------------------
// MFMA attention (R12 structure: V staged fp16 directly into tr-read layout,
// PV via ds_read_b64_tr_b16; no transpose pass). R14: XCD swizzle -- 2 heads
// per XCD so each XCD's K/V/Q head-slices (~1.2 MB) stay L2-resident.
// ---------------------------------------------------------------------------
struct AttnSmem {
    union {
        ushort Ks[192 * 64];        // [key][dg] ; dg holds dims 8*(dg^(key&7))
        ushort Vs[48 * 256];        // 48 tr-read tiles (fp16)
    } u;
    float S[32][195];
    float Rsum[32];
};

__global__ __launch_bounds__(256) void attn_kernel(
    const ushort* __restrict__ q, const ushort* __restrict__ k,
    const ushort* __restrict__ v, ushort* __restrict__ ctx)
{
    __shared__ AttnSmem sm;

    const int tid  = threadIdx.x;
    const int lane = tid & 63, w = tid >> 6;
    const int ln15 = lane & 15, quad = lane >> 4;

    // XCD decode: 1536 blocks = 8 xcd x 2 heads x (24 t0 x 4 r)
    const int lid = blockIdx.x;
    const int xcd = lid & 7, s0 = lid >> 3;     // s0: 0..191
    const int h   = xcd * 2 + (s0 / 96);
    const int rem = s0 % 96;
    const int t0  = (rem % 24) * 32;
    const int r   = rem / 24;
    const int hoff = h * DH;

    // ---- stage K (192 keys x 64 dims) via glds, 6 ops/wave -----------------
    {
        const int kr = lane >> 3;                   // key-in-op 0..7
        const int swz = ((lane & 7) ^ kr) * 8;      // XOR swizzle on global dim
#pragma unroll
        for (int ci = w * 6; ci < w * 6 + 6; ++ci) {
            int key = ci * 8 + kr;
            long grow = 4L * (t0 - 160 + key) + r;  // may be negative -> q buffer
            gload_lds16(k + grow * DM + hoff + swz, &sm.u.Ks[ci * 512]);
        }
    }

    // ---- Q A-frags direct from global (wave w owns qtile w>>1) -------------
    const int qt = w >> 1;
    short8 qf0, qf1;
    {
        int qrow = qt * 16 + ln15;
        const ushort* gq = q + (4L * (t0 + qrow) + r) * DM + hoff + quad * 8;
        qf0 = *(const short8*)gq;
        qf1 = *(const short8*)(gq + 32);
    }

    __syncthreads();   // barrier 1: Ks staged (vmcnt drained by sync)

    // ---- QK^T: wave w -> qtile w>>1, ktiles (w&1)*6 .. +5 ------------------
    {
        const floatx4 zero = {0.f, 0.f, 0.f, 0.f};
        const int kt0 = (w & 1) * 6;
        const int lb  = ln15 & 7;
#pragma unroll
        for (int kk2 = 0; kk2 < 6; ++kk2) {
            const int kt  = kt0 + kk2;
            const int key = kt * 16 + ln15;
            short8 b0 = *(const short8*)&sm.u.Ks[key * 64 + ((quad ^ lb) << 3)];
            short8 b1 = *(const short8*)&sm.u.Ks[key * 64 + (((4 + quad) ^ lb) << 3)];
            floatx4 acc = zero;
            acc = __builtin_amdgcn_mfma_f32_16x16x32_bf16(qf0, b0, acc, 0, 0, 0);
            acc = __builtin_amdgcn_mfma_f32_16x16x32_bf16(qf1, b1, acc, 0, 0, 0);
            const int tp = t0 - 160 + key;          // key slot time
#pragma unroll
            for (int rg = 0; rg < 4; ++rg) {
                int qrow = qt * 16 + quad * 4 + rg;
                int tq = t0 + qrow;
                bool ok = (tp >= 0) && (tp <= tq) && (tp > tq - WIN);
                sm.S[qrow][key] = ok ? acc[rg] : -1e30f;
            }
        }
    }

    __syncthreads();   // barrier 2: S complete, Ks reads done (Vs may alias)

    // ---- stage V (fp16) into tr-read layout via glds, 6 ops/wave -----------
    {
#pragma unroll
        for (int i = 0; i < 6; ++i) {
            const int o  = w * 6 + i;               // op 0..23
            const int c  = o * 64 + lane;           // 16-B chunk index
            const int hh = c & 1, jj = (c >> 1) & 3, qq = (c >> 3) & 3;
            const int T  = c >> 5;
            const int p  = T & 1, dtt = (T >> 1) & 3, kc = T >> 3;
            const int key = kc * 32 + qq * 8 + p * 4 + jj;
            const int dim = dtt * 16 + hh * 8;
            long grow = 4L * (t0 - 160 + key) + r;  // may be negative -> masked
            gload_lds16(v + grow * DM + hoff + dim, &sm.u.Vs[o * 512]);
        }
    }

    // ---- softmax: 8 threads/row, stride-8 slot ownership -------------------
    // (V DMA latency hides under this; barrier 3 drains vmcnt.)
    {
        const int sq = tid >> 3, part = tid & 7;
        float m = -1e30f;
#pragma unroll
        for (int j = 0; j < 24; ++j) m = fmaxf(m, sm.S[sq][part + 8 * j]);
#pragma unroll
        for (int o = 1; o < 8; o <<= 1) m = fmaxf(m, __shfl_xor(m, o));
        float sum = 0.f;
#pragma unroll
        for (int j = 0; j < 24; ++j) {
            int ks = part + 8 * j;
            float e = __expf(sm.S[sq][ks] - m);
            sm.S[sq][ks] = e;
            sum += e;
        }
#pragma unroll
        for (int o = 1; o < 8; o <<= 1) sum += __shfl_xor(sum, o);
        if (part == 0) sm.Rsum[sq] = 1.0f / sum;
    }

    __syncthreads();   // barrier 3: Vs + P(S) + Rsum ready (vmcnt drained)

    // ---- PV: wave w -> qtile w&1, dtiles (w>>1)*2 .. +1 --------------------
    {
        const floatx4 zero = {0.f, 0.f, 0.f, 0.f};
        const int qtp = w & 1, dh = w >> 1;
        floatx4 o0 = zero, o1 = zero;
        // byte addr: tile(kc,dt,p) at kc*4096 + dt*1024 + p*512; dt0 = dh*2.
        const unsigned vbase =
            (unsigned)(size_t)(__attribute__((address_space(3))) ushort*)&sm.u.Vs[0]
            + lane * 8 + dh * 2048;
#pragma unroll
        for (int kc = 0; kc < 6; ++kc) {
            const float* ps = &sm.S[qtp * 16 + ln15][kc * 32 + quad * 8];
            half8 pa;
#pragma unroll
            for (int u = 0; u < 8; ++u) pa[u] = (_Float16)ps[u];
            half4 a0, a1, b0, b1;
            asm volatile(
                "ds_read_b64_tr_b16 %0, %4\n\t"
                "ds_read_b64_tr_b16 %1, %4 offset:512\n\t"
                "ds_read_b64_tr_b16 %2, %4 offset:1024\n\t"
                "ds_read_b64_tr_b16 %3, %4 offset:1536\n\t"
                "s_waitcnt lgkmcnt(0)"
                : "=&v"(a0), "=&v"(a1), "=&v"(b0), "=&v"(b1)
                : "v"(vbase + kc * 4096));
            __builtin_amdgcn_sched_barrier(0);      // rule #18 fence
            half8 vb0 = __builtin_shufflevector(a0, a1, 0, 1, 2, 3, 4, 5, 6, 7);
            half8 vb1 = __builtin_shufflevector(b0, b1, 0, 1, 2, 3, 4, 5, 6, 7);
            o0 = __builtin_amdgcn_mfma_f32_16x16x32_f16(pa, vb0, o0, 0, 0, 0);
            o1 = __builtin_amdgcn_mfma_f32_16x16x32_f16(pa, vb1, o1, 0, 0, 0);
        }
#pragma unroll
        for (int rg = 0; rg < 4; ++rg) {
            int qrow = qtp * 16 + quad * 4 + rg;
            float rs = sm.Rsum[qrow];
            long orow = 4L * (t0 + qrow) + r;
            ushort* cp = ctx + orow * DM + hoff + dh * 32 + ln15;
            cp[0]  = f2bf(o0[rg] * rs);
            cp[16] = f2bf(o1[rg] * rs);
        }
    }
}

// ---------------------------------------------------------------------------
// ws layout: q, k, ctx bf16; v fp16; x, Wq, Wk, Wv, Wo bf16.
// ---------------------------------------------------------------------------
extern "C" void kernel_launch(void* const* d_in, const int* in_sizes, int n_in,
                              void* d_out, int out_size, void* d_ws, size_t ws_size,
                              hipStream_t stream)
{
    const float* x    = (const float*)d_in[0];
    const float* beta = (const float*)d_in[1];
    const float* Wq   = (const float*)d_in[2];
    const float* bq   = (const float*)d_in[3];
    const float* Wk   = (const float*)d_in[4];
    const float* bk   = (const float*)d_in[5];
    const float* Wv   = (const float*)d_in[6];
    const float* bv   = (const float*)d_in[7];
    const float* Wo   = (const float*)d_in[8];
    const float* bo   = (const float*)d_in[9];

    ushort* qb   = (ushort*)d_ws;
    ushort* kb   = qb   + (size_t)SEQ * DM;
    ushort* vb   = kb   + (size_t)SEQ * DM;
    ushort* ctxb = vb   + (size_t)SEQ * DM;
    ushort* xb   = ctxb + (size_t)SEQ * DM;
    ushort* Wqb  = xb   + (size_t)SEQ * DM;
    ushort* Wkb  = Wqb  + (size_t)DM * DM;
    ushort* Wvb  = Wkb  + (size_t)DM * DM;
    ushort* Wob  = Wvb  + (size_t)DM * DM;
    float*  out  = (float*)d_out;

    dim3 gcv(SEQ * DM / 4 / 256, 5);
    convert_kernel<<<gcv, 256, 0, stream>>>(x, Wq, Wk, Wv, Wo, xb, Wqb, Wkb, Wvb, Wob);

    qkv_kernel<<<dim3(1152), 256, 0, stream>>>(xb, Wqb, bq, Wkb, bk, Wvb, bv, beta, qb, kb, vb);

    attn_kernel<<<dim3(1536), 256, 0, stream>>>(qb, kb, vb, ctxb);

    out_kernel<<<dim3(768), 256, 0, stream>>>(ctxb, Wob, bo, out);
}